// Round 4
// baseline (552.146 us; speedup 1.0000x reference)
//
#include <hip/hip_runtime.h>
#include <math.h>

typedef __attribute__((ext_vector_type(8))) short short8;
typedef __attribute__((ext_vector_type(8))) unsigned short ushort8;
typedef __attribute__((ext_vector_type(4))) float f32x4;

#define NH 16
#define HD 64
#define SEQ 1024
#define NB 8
#define CH 1024
#define TD 256
#define SLAB_BH 32
#define GROW 1025  // flat row stride of G' (the skew trick)

__device__ __forceinline__ unsigned short f2bf(float f) {
  union { float f; unsigned int u; } v; v.f = f;
  unsigned int r = v.u + 0x7FFFu + ((v.u >> 16) & 1u);
  return (unsigned short)(r >> 16);
}
__device__ __forceinline__ float bf2f(unsigned short s) {
  union { unsigned int u; float f; } v; v.u = ((unsigned int)s) << 16;
  return v.f;
}
__device__ __forceinline__ void gload_lds16(const unsigned short* g, unsigned short* l) {
  __builtin_amdgcn_global_load_lds(
      (const __attribute__((address_space(1))) unsigned int*)g,
      (__attribute__((address_space(3))) unsigned int*)l, 16, 0, 0);
}

// ---------------- time projection (fp32) ----------------
__global__ __launch_bounds__(256) void time_proj_kernel(
    const float* __restrict__ time_emb, const float* __restrict__ W_time,
    const float* __restrict__ b_time, float* __restrict__ tqkv) {
  int idx = blockIdx.x * 256 + threadIdx.x;
  if (idx >= NB * 3072) return;
  int b = idx / 3072, c = idx % 3072;
  float s = b_time[c];
  for (int t = 0; t < TD; ++t) s += time_emb[b * TD + t] * W_time[t * 3072 + c];
  tqkv[idx] = s;
}

// ---------------- Er fp32 -> bf16 ----------------
__global__ __launch_bounds__(256) void er_convert_kernel(
    const float* __restrict__ Er, unsigned short* __restrict__ Er_bf) {
  int i = blockIdx.x * 256 + threadIdx.x;
  if (i < SEQ * HD) Er_bf[i] = f2bf(Er[i]);
}

// ---------------- fp32 -> bf16 vector convert ----------------
__global__ __launch_bounds__(256) void convert_bf_kernel(
    const float* __restrict__ in, unsigned short* __restrict__ out, int n8) {
  int i = blockIdx.x * 256 + threadIdx.x;
  if (i >= n8) return;
  float4 a = ((const float4*)in)[2 * i];
  float4 b = ((const float4*)in)[2 * i + 1];
  ushort8 o;
  o[0] = f2bf(a.x); o[1] = f2bf(a.y); o[2] = f2bf(a.z); o[3] = f2bf(a.w);
  o[4] = f2bf(b.x); o[5] = f2bf(b.y); o[6] = f2bf(b.z); o[7] = f2bf(b.w);
  ((ushort8*)out)[i] = o;
}

// ---------------- fp32 W[R][C] -> bf16 Wt[C][R] ----------------
__global__ __launch_bounds__(256) void transpose_bf_kernel(
    const float* __restrict__ W, unsigned short* __restrict__ Wt, int R, int Cc) {
  __shared__ float T[64][65];
  int r0 = blockIdx.y * 64, c0 = blockIdx.x * 64;
  for (int idx = threadIdx.x; idx < 4096; idx += 256) {
    int r = idx >> 6, c = idx & 63;
    T[r][c] = W[(size_t)(r0 + r) * Cc + c0 + c];
  }
  __syncthreads();
  for (int idx = threadIdx.x; idx < 4096; idx += 256) {
    int c = idx >> 6, r = idx & 63;
    Wt[(size_t)(c0 + c) * R + r0 + r] = f2bf(T[r][c]);
  }
}

// ---------------- QKV GEMM: bf16 MFMA, [kq][mr] LDS relabel ----------------
__global__ __launch_bounds__(256) void qkv_gemm_mfma(
    const unsigned short* __restrict__ A, const unsigned short* __restrict__ Bt,
    const float* __restrict__ bqkv, const float* __restrict__ tqkv,
    unsigned short* __restrict__ qb, unsigned short* __restrict__ kb,
    unsigned short* __restrict__ vb) {
  __shared__ unsigned short As[128 * 32];
  __shared__ unsigned short Bs[128 * 32];
  const int m0 = blockIdx.x * 128, n0 = blockIdx.y * 128;
  const int tid = threadIdx.x, l = tid & 63, w = tid >> 6;
  const int wm = w >> 1, wn = w & 1;
  const int grp = l >> 4, col = l & 15;
  f32x4 acc[4][4];
#pragma unroll
  for (int mi = 0; mi < 4; ++mi)
#pragma unroll
    for (int ni = 0; ni < 4; ++ni) acc[mi][ni] = (f32x4){0.f, 0.f, 0.f, 0.f};

  for (int k0 = 0; k0 < 1024; k0 += 32) {
    __syncthreads();
#pragma unroll
    for (int i = 0; i < 2; ++i) {
      int g = i * 256 + w * 64 + l;
      int mr = g & 127, kq = g >> 7;  // granule relabel: LDS = [kq][mr]
      gload_lds16(A + (size_t)(m0 + mr) * 1024 + k0 + kq * 8,
                  &As[(i * 256 + w * 64) * 8]);
      gload_lds16(Bt + (size_t)(n0 + mr) * 1024 + k0 + kq * 8,
                  &Bs[(i * 256 + w * 64) * 8]);
    }
    __syncthreads();
    short8 af[4], bfv[4];
#pragma unroll
    for (int mi = 0; mi < 4; ++mi)
      af[mi] = *(const short8*)&As[(grp * 128 + wm * 64 + mi * 16 + col) * 8];
#pragma unroll
    for (int ni = 0; ni < 4; ++ni)
      bfv[ni] = *(const short8*)&Bs[(grp * 128 + wn * 64 + ni * 16 + col) * 8];
#pragma unroll
    for (int mi = 0; mi < 4; ++mi)
#pragma unroll
      for (int ni = 0; ni < 4; ++ni)
        acc[mi][ni] = __builtin_amdgcn_mfma_f32_16x16x32_bf16(af[mi], bfv[ni], acc[mi][ni], 0, 0, 0);
  }

  const int bidx = m0 >> 10;
  const int which = n0 >> 10;
  unsigned short* dst = (which == 0) ? qb : (which == 1) ? kb : vb;
  float biasv[4];
  int hhv[4], dv[4];
#pragma unroll
  for (int ni = 0; ni < 4; ++ni) {
    int c = n0 + wn * 64 + ni * 16 + col;
    biasv[ni] = bqkv[c] + tqkv[bidx * 3072 + c];
    int cc = c & 1023;
    hhv[ni] = cc >> 6;
    dv[ni] = cc & 63;
  }
#pragma unroll
  for (int mi = 0; mi < 4; ++mi)
#pragma unroll
    for (int rr = 0; rr < 4; ++rr) {
      int row = m0 + wm * 64 + mi * 16 + grp * 4 + rr;
      int nn = row & 1023;
#pragma unroll
      for (int ni = 0; ni < 4; ++ni)
        dst[(((size_t)(bidx * 16 + hhv[ni])) * 1024 + nn) * 64 + dv[ni]] =
            f2bf(acc[mi][ni][rr] + biasv[ni]);
    }
}

// ---------------- output projection: bf16 MFMA, same relabel ----------------
__global__ __launch_bounds__(256) void out_gemm_mfma(
    const unsigned short* __restrict__ A, const unsigned short* __restrict__ Bt,
    const float* __restrict__ bias, float* __restrict__ out) {
  __shared__ unsigned short As[128 * 32];
  __shared__ unsigned short Bs[128 * 32];
  const int m0 = blockIdx.x * 128, n0 = blockIdx.y * 128;
  const int tid = threadIdx.x, l = tid & 63, w = tid >> 6;
  const int wm = w >> 1, wn = w & 1;
  const int grp = l >> 4, col = l & 15;
  f32x4 acc[4][4];
#pragma unroll
  for (int mi = 0; mi < 4; ++mi)
#pragma unroll
    for (int ni = 0; ni < 4; ++ni) acc[mi][ni] = (f32x4){0.f, 0.f, 0.f, 0.f};

  for (int k0 = 0; k0 < 1024; k0 += 32) {
    __syncthreads();
#pragma unroll
    for (int i = 0; i < 2; ++i) {
      int g = i * 256 + w * 64 + l;
      int mr = g & 127, kq = g >> 7;
      gload_lds16(A + (size_t)(m0 + mr) * 1024 + k0 + kq * 8,
                  &As[(i * 256 + w * 64) * 8]);
      gload_lds16(Bt + (size_t)(n0 + mr) * 1024 + k0 + kq * 8,
                  &Bs[(i * 256 + w * 64) * 8]);
    }
    __syncthreads();
    short8 af[4], bfv[4];
#pragma unroll
    for (int mi = 0; mi < 4; ++mi)
      af[mi] = *(const short8*)&As[(grp * 128 + wm * 64 + mi * 16 + col) * 8];
#pragma unroll
    for (int ni = 0; ni < 4; ++ni)
      bfv[ni] = *(const short8*)&Bs[(grp * 128 + wn * 64 + ni * 16 + col) * 8];
#pragma unroll
    for (int mi = 0; mi < 4; ++mi)
#pragma unroll
      for (int ni = 0; ni < 4; ++ni)
        acc[mi][ni] = __builtin_amdgcn_mfma_f32_16x16x32_bf16(af[mi], bfv[ni], acc[mi][ni], 0, 0, 0);
  }
  float bv[4];
#pragma unroll
  for (int ni = 0; ni < 4; ++ni) bv[ni] = bias[n0 + wn * 64 + ni * 16 + col];
#pragma unroll
  for (int mi = 0; mi < 4; ++mi)
#pragma unroll
    for (int rr = 0; rr < 4; ++rr) {
      int row = m0 + wm * 64 + mi * 16 + grp * 4 + rr;
#pragma unroll
      for (int ni = 0; ni < 4; ++ni) {
        int c = n0 + wn * 64 + ni * 16 + col;
        out[(size_t)row * 1024 + c] = acc[mi][ni][rr] + bv[ni];
      }
    }
}

// ---------------- G' GEMM: G'[n*1025 + j] = q_n . Er[j] (clean, no scatter) ----------------
__global__ __launch_bounds__(256) void g_gemm2(
    const unsigned short* __restrict__ qb, int bh_base,
    const unsigned short* __restrict__ Er_bf,
    unsigned short* __restrict__ Gp) {
  const int n0 = blockIdx.x * 64;
  const int jq = blockIdx.y;       // 0..3
  const int bhl = blockIdx.z;
  const int bh = bh_base + bhl;
  const int tid = threadIdx.x, l = tid & 63, w = tid >> 6;
  const int grp = l >> 4, col = l & 15;
  const int jw = jq * 256 + w * 64;

  short8 aq[4][2];
#pragma unroll
  for (int rf = 0; rf < 4; ++rf)
#pragma unroll
    for (int dc = 0; dc < 2; ++dc)
      aq[rf][dc] = *(const short8*)(qb + ((size_t)bh * SEQ + n0 + rf * 16 + col) * HD + dc * 32 + grp * 8);

  f32x4 acc[4][4];
#pragma unroll
  for (int rf = 0; rf < 4; ++rf)
#pragma unroll
    for (int cf = 0; cf < 4; ++cf) acc[rf][cf] = (f32x4){0.f, 0.f, 0.f, 0.f};

#pragma unroll
  for (int cf = 0; cf < 4; ++cf)
#pragma unroll
    for (int dc = 0; dc < 2; ++dc) {
      short8 bfrag = *(const short8*)(Er_bf + (size_t)(jw + cf * 16 + col) * HD + dc * 32 + grp * 8);
#pragma unroll
      for (int rf = 0; rf < 4; ++rf)
        acc[rf][cf] = __builtin_amdgcn_mfma_f32_16x16x32_bf16(aq[rf][dc], bfrag, acc[rf][cf], 0, 0, 0);
    }

#pragma unroll
  for (int rf = 0; rf < 4; ++rf)
#pragma unroll
    for (int cf = 0; cf < 4; ++cf)
#pragma unroll
      for (int rr = 0; rr < 4; ++rr) {
        int n = n0 + rf * 16 + grp * 4 + rr;
        int j = jw + cf * 16 + col;
        Gp[((size_t)(bhl * SEQ + n)) * GROW + j] = f2bf(acc[rf][cf][rr]);
      }
}

// ---------------- flash attention: rel via flat-G' band staged in LDS ----------------
__global__ __launch_bounds__(256) void attn_kernel(
    const unsigned short* __restrict__ qb, const unsigned short* __restrict__ kb,
    const unsigned short* __restrict__ vb, const unsigned short* __restrict__ Gp,
    unsigned short* __restrict__ attn_o, int bh_base) {
  __shared__ __align__(16) unsigned short Ks[64][72];
  __shared__ __align__(16) unsigned short Vt[64][72];
  __shared__ __align__(16) unsigned short Pw[4][16][72];
  __shared__ __align__(16) unsigned short Band[64][72];

  // XCD-chunked remap: each XCD owns 4 consecutive bh (K/V L2-resident)
  const int wg = blockIdx.x + 16 * blockIdx.y;  // 512 wgs
  const int nid = (wg & 7) * 64 + (wg >> 3);
  const int bhl = nid >> 4;
  const int n0 = (nid & 15) * 64;
  const int bh = bh_base + bhl;
  const int b = bh >> 4, h = bh & 15;
  const int tid = threadIdx.x, lane = tid & 63, wq = tid >> 6;
  const int grp = lane >> 4, col = lane & 15;
  const int n0w = n0 + wq * 16;

  short8 aq[2];
#pragma unroll
  for (int dc = 0; dc < 2; ++dc)
    aq[dc] = *(const short8*)(qb + ((size_t)(bh * SEQ + n0w + col)) * HD + dc * 32 + grp * 8);

  f32x4 acco[4];
#pragma unroll
  for (int oc = 0; oc < 4; ++oc) acco[oc] = (f32x4){0.f, 0.f, 0.f, 0.f};
  float mrun[4], lrun[4];
#pragma unroll
  for (int r = 0; r < 4; ++r) { mrun[r] = -INFINITY; lrun[r] = 0.f; }

  const float scale = 0.125f;
  const unsigned short* kbh = kb + (size_t)bh * SEQ * HD;
  const unsigned short* vbh = vb + (size_t)bh * SEQ * HD;
  // per-row flat base for G' band: s8(r) = (bhl*1024+n)*1025 + 1016 + m0 - n
  const size_t gflat0 = (size_t)(bhl * SEQ + n0) * GROW;

  for (int m0 = 0; m0 < SEQ; m0 += 64) {
    __syncthreads();
    // stage K rows, V^T
    {
      int rowa = tid >> 3;
      int d0 = (tid & 7) * 8;
#pragma unroll
      for (int it = 0; it < 2; ++it) {
        int m = rowa + it * 32;
        short8 kv = *(const short8*)(kbh + (size_t)(m0 + m) * HD + d0);
        *(short8*)&Ks[m][d0] = kv;
        short8 vv = *(const short8*)(vbh + (size_t)(m0 + m) * HD + d0);
#pragma unroll
        for (int e = 0; e < 8; ++e) Vt[d0 + e][m] = (unsigned short)vv[e];
      }
    }
    // stage rel band: row r covers G'flat[s8(r) .. +72), value(r,c)=Band[r][7+c]
    for (int idx = tid; idx < 576; idx += 256) {
      int r = idx / 9, seg = idx - r * 9;
      size_t s8 = gflat0 + (size_t)r * GROW + (size_t)(1016 + m0 - (n0 + r));
      short8 gvv = *(const short8*)(Gp + s8 + seg * 8);
      *(short8*)&Band[r][seg * 8] = gvv;
    }
    __syncthreads();
    // QK^T
    f32x4 acc[4];
#pragma unroll
    for (int mc = 0; mc < 4; ++mc) acc[mc] = (f32x4){0.f, 0.f, 0.f, 0.f};
#pragma unroll
    for (int mc = 0; mc < 4; ++mc)
#pragma unroll
      for (int dc = 0; dc < 2; ++dc) {
        short8 bk = *(const short8*)&Ks[mc * 16 + col][dc * 32 + grp * 8];
        acc[mc] = __builtin_amdgcn_mfma_f32_16x16x32_bf16(aq[dc], bk, acc[mc], 0, 0, 0);
      }
    // online softmax
#pragma unroll
    for (int r = 0; r < 4; ++r) {
      int dr = wq * 16 + grp * 4 + r;
      int n = n0 + dr;
      float s[4];
#pragma unroll
      for (int mc = 0; mc < 4; ++mc) {
        float g = bf2f(Band[dr][7 + mc * 16 + col]);
        int m = m0 + mc * 16 + col;
        if (m == n + 1) g = 0.f;  // skew's dropped-pad diagonal
        s[mc] = acc[mc][r] * scale + g;
      }
      float mx = fmaxf(fmaxf(s[0], s[1]), fmaxf(s[2], s[3]));
#pragma unroll
      for (int off = 1; off < 16; off <<= 1) mx = fmaxf(mx, __shfl_xor(mx, off));
      float mnew = fmaxf(mrun[r], mx);
      float cr = __expf(mrun[r] - mnew);
      float ls = 0.f;
      float p[4];
#pragma unroll
      for (int mc = 0; mc < 4; ++mc) { p[mc] = __expf(s[mc] - mnew); ls += p[mc]; }
#pragma unroll
      for (int off = 1; off < 16; off <<= 1) ls += __shfl_xor(ls, off);
      lrun[r] = lrun[r] * cr + ls;
      mrun[r] = mnew;
#pragma unroll
      for (int oc = 0; oc < 4; ++oc) acco[oc][r] *= cr;
#pragma unroll
      for (int mc = 0; mc < 4; ++mc) Pw[wq][grp * 4 + r][mc * 16 + col] = f2bf(p[mc]);
    }
    // PV
    short8 ap[2];
#pragma unroll
    for (int kc = 0; kc < 2; ++kc)
      ap[kc] = *(const short8*)&Pw[wq][col][kc * 32 + grp * 8];
#pragma unroll
    for (int oc = 0; oc < 4; ++oc)
#pragma unroll
      for (int kc = 0; kc < 2; ++kc) {
        short8 bv = *(const short8*)&Vt[oc * 16 + col][kc * 32 + grp * 8];
        acco[oc] = __builtin_amdgcn_mfma_f32_16x16x32_bf16(ap[kc], bv, acco[oc], 0, 0, 0);
      }
  }
#pragma unroll
  for (int oc = 0; oc < 4; ++oc)
#pragma unroll
    for (int r = 0; r < 4; ++r) {
      int n = n0w + grp * 4 + r;
      int d = oc * 16 + col;
      attn_o[((size_t)(b * SEQ + n)) * CH + h * HD + d] = f2bf(acco[oc][r] / lrun[r]);
    }
}

extern "C" void kernel_launch(void* const* d_in, const int* in_sizes, int n_in,
                              void* d_out, int out_size, void* d_ws, size_t ws_size,
                              hipStream_t stream) {
  const float* x        = (const float*)d_in[0];
  const float* time_emb = (const float*)d_in[1];
  const float* W_qkv    = (const float*)d_in[2];
  const float* b_qkv    = (const float*)d_in[3];
  const float* W_time   = (const float*)d_in[4];
  const float* b_time   = (const float*)d_in[5];
  const float* W_out    = (const float*)d_in[6];
  const float* b_out    = (const float*)d_in[7];
  const float* Er       = (const float*)d_in[8];
  float* out = (float*)d_out;

  char* p = (char*)d_ws;
  float* tqkv = (float*)p;                      p += 98304;
  unsigned short* qb = (unsigned short*)p;      p += 16777216;
  unsigned short* kb = (unsigned short*)p;      p += 16777216;
  unsigned short* vb = (unsigned short*)p;      p += 16777216;
  unsigned short* attn_o = (unsigned short*)p;  p += 16777216;
  unsigned short* Er_bf = (unsigned short*)p;   p += 131072;
  unsigned short* Wout_t = (unsigned short*)p;  p += 2097152;
  unsigned short* x_bf = (unsigned short*)p;               // 16 MB
  unsigned short* Wqkv_t = x_bf + (size_t)8388608;         // 6 MB
  unsigned short* Gp = (unsigned short*)p;                 // 67.2 MB (+pad), aliases x_bf (dead)

  er_convert_kernel<<<256, 256, 0, stream>>>(Er, Er_bf);
  time_proj_kernel<<<96, 256, 0, stream>>>(time_emb, W_time, b_time, tqkv);
  convert_bf_kernel<<<4096, 256, 0, stream>>>(x, x_bf, 1048576);
  transpose_bf_kernel<<<dim3(48, 16), 256, 0, stream>>>(W_qkv, Wqkv_t, 1024, 3072);
  transpose_bf_kernel<<<dim3(16, 16), 256, 0, stream>>>(W_out, Wout_t, 1024, 1024);
  qkv_gemm_mfma<<<dim3(64, 24), 256, 0, stream>>>(x_bf, Wqkv_t, b_qkv, tqkv, qb, kb, vb);
  for (int s = 0; s < 4; ++s) {
    int bh_base = s * SLAB_BH;
    g_gemm2<<<dim3(16, 4, SLAB_BH), 256, 0, stream>>>(qb, bh_base, Er_bf, Gp);
    attn_kernel<<<dim3(16, SLAB_BH), 256, 0, stream>>>(qb, kb, vb, Gp, attn_o, bh_base);
  }
  out_gemm_mfma<<<dim3(64, 8), 256, 0, stream>>>(attn_o, Wout_t, b_out, out);
}

// Round 5
// 447.749 us; speedup vs baseline: 1.2332x; 1.2332x over previous
//
#include <hip/hip_runtime.h>
#include <math.h>

typedef __attribute__((ext_vector_type(8))) short short8;
typedef __attribute__((ext_vector_type(8))) unsigned short ushort8;
typedef __attribute__((ext_vector_type(4))) float f32x4;

#define NH 16
#define HD 64
#define SEQ 1024
#define NB 8
#define CH 1024
#define TD 256
#define SLAB_BH 32
#define GROW 1025  // flat row stride of G' (the skew trick)

__device__ __forceinline__ unsigned short f2bf(float f) {
  union { float f; unsigned int u; } v; v.f = f;
  unsigned int r = v.u + 0x7FFFu + ((v.u >> 16) & 1u);
  return (unsigned short)(r >> 16);
}
__device__ __forceinline__ float bf2f(unsigned short s) {
  union { unsigned int u; float f; } v; v.u = ((unsigned int)s) << 16;
  return v.f;
}
__device__ __forceinline__ void gload_lds16(const unsigned short* g, unsigned short* l) {
  __builtin_amdgcn_global_load_lds(
      (const __attribute__((address_space(1))) unsigned int*)g,
      (__attribute__((address_space(3))) unsigned int*)l, 16, 0, 0);
}

// ---------------- time projection (fp32) ----------------
__global__ __launch_bounds__(256) void time_proj_kernel(
    const float* __restrict__ time_emb, const float* __restrict__ W_time,
    const float* __restrict__ b_time, float* __restrict__ tqkv) {
  int idx = blockIdx.x * 256 + threadIdx.x;
  if (idx >= NB * 3072) return;
  int b = idx / 3072, c = idx % 3072;
  float s = b_time[c];
  for (int t = 0; t < TD; ++t) s += time_emb[b * TD + t] * W_time[t * 3072 + c];
  tqkv[idx] = s;
}

// ---------------- Er fp32 -> bf16 ----------------
__global__ __launch_bounds__(256) void er_convert_kernel(
    const float* __restrict__ Er, unsigned short* __restrict__ Er_bf) {
  int i = blockIdx.x * 256 + threadIdx.x;
  if (i < SEQ * HD) Er_bf[i] = f2bf(Er[i]);
}

// ---------------- fp32 -> bf16 vector convert ----------------
__global__ __launch_bounds__(256) void convert_bf_kernel(
    const float* __restrict__ in, unsigned short* __restrict__ out, int n8) {
  int i = blockIdx.x * 256 + threadIdx.x;
  if (i >= n8) return;
  float4 a = ((const float4*)in)[2 * i];
  float4 b = ((const float4*)in)[2 * i + 1];
  ushort8 o;
  o[0] = f2bf(a.x); o[1] = f2bf(a.y); o[2] = f2bf(a.z); o[3] = f2bf(a.w);
  o[4] = f2bf(b.x); o[5] = f2bf(b.y); o[6] = f2bf(b.z); o[7] = f2bf(b.w);
  ((ushort8*)out)[i] = o;
}

// ---------------- fp32 W[R][C] -> bf16 Wt[C][R] ----------------
__global__ __launch_bounds__(256) void transpose_bf_kernel(
    const float* __restrict__ W, unsigned short* __restrict__ Wt, int R, int Cc) {
  __shared__ float T[64][65];
  int r0 = blockIdx.y * 64, c0 = blockIdx.x * 64;
  for (int idx = threadIdx.x; idx < 4096; idx += 256) {
    int r = idx >> 6, c = idx & 63;
    T[r][c] = W[(size_t)(r0 + r) * Cc + c0 + c];
  }
  __syncthreads();
  for (int idx = threadIdx.x; idx < 4096; idx += 256) {
    int c = idx >> 6, r = idx & 63;
    Wt[(size_t)(c0 + c) * R + r0 + r] = f2bf(T[r][c]);
  }
}

// ---------------- QKV GEMM: bf16 MFMA, round-3 layout (proven 72us) ----------------
// q -> qb[bh][n][d]; k -> ksw[bh][n][d ^ ((n&7)<<3)]; v -> vtsw[bh][d][n ^ ((d&7)<<3)]
__global__ __launch_bounds__(256) void qkv_gemm_mfma(
    const unsigned short* __restrict__ A, const unsigned short* __restrict__ Bt,
    const float* __restrict__ bqkv, const float* __restrict__ tqkv,
    unsigned short* __restrict__ qb, unsigned short* __restrict__ ksw,
    unsigned short* __restrict__ vtsw) {
  __shared__ unsigned short As[128 * 32];
  __shared__ unsigned short Bs[128 * 32];
  const int m0 = blockIdx.x * 128, n0 = blockIdx.y * 128;
  const int tid = threadIdx.x, l = tid & 63, w = tid >> 6;
  const int wm = w >> 1, wn = w & 1;
  const int grp = l >> 4, col = l & 15;
  f32x4 acc[4][4];
#pragma unroll
  for (int mi = 0; mi < 4; ++mi)
#pragma unroll
    for (int ni = 0; ni < 4; ++ni) acc[mi][ni] = (f32x4){0.f, 0.f, 0.f, 0.f};

  for (int k0 = 0; k0 < 1024; k0 += 32) {
    __syncthreads();
#pragma unroll
    for (int i = 0; i < 2; ++i) {
      int seg = i * 256 + w * 64 + l;
      int mr = seg >> 2, kq = seg & 3;
      gload_lds16(A + (size_t)(m0 + mr) * 1024 + k0 + kq * 8,
                  &As[(i * 256 + w * 64) * 8]);
      gload_lds16(Bt + (size_t)(n0 + mr) * 1024 + k0 + kq * 8,
                  &Bs[(i * 256 + w * 64) * 8]);
    }
    __syncthreads();
    short8 af[4], bfv[4];
#pragma unroll
    for (int mi = 0; mi < 4; ++mi)
      af[mi] = *(const short8*)&As[(wm * 64 + mi * 16 + col) * 32 + grp * 8];
#pragma unroll
    for (int ni = 0; ni < 4; ++ni)
      bfv[ni] = *(const short8*)&Bs[(wn * 64 + ni * 16 + col) * 32 + grp * 8];
#pragma unroll
    for (int mi = 0; mi < 4; ++mi)
#pragma unroll
      for (int ni = 0; ni < 4; ++ni)
        acc[mi][ni] = __builtin_amdgcn_mfma_f32_16x16x32_bf16(af[mi], bfv[ni], acc[mi][ni], 0, 0, 0);
  }

  const int bidx = m0 >> 10;
  const int which = n0 >> 10;
  float biasv[4];
  int hhv[4], dv[4];
#pragma unroll
  for (int ni = 0; ni < 4; ++ni) {
    int c = n0 + wn * 64 + ni * 16 + col;
    biasv[ni] = bqkv[c] + tqkv[bidx * 3072 + c];
    int cc = c & 1023;
    hhv[ni] = cc >> 6;
    dv[ni] = cc & 63;
  }
#pragma unroll
  for (int mi = 0; mi < 4; ++mi)
#pragma unroll
    for (int rr = 0; rr < 4; ++rr) {
      int row = m0 + wm * 64 + mi * 16 + grp * 4 + rr;
      int nn = row & 1023;
#pragma unroll
      for (int ni = 0; ni < 4; ++ni) {
        unsigned short val = f2bf(acc[mi][ni][rr] + biasv[ni]);
        size_t bhh = (size_t)(bidx * 16 + hhv[ni]);
        if (which == 0)
          qb[(bhh * 1024 + nn) * 64 + dv[ni]] = val;
        else if (which == 1)
          ksw[(bhh * 1024 + nn) * 64 + (dv[ni] ^ ((nn & 7) << 3))] = val;
        else
          vtsw[(bhh * 64 + dv[ni]) * 1024 + (nn ^ ((dv[ni] & 7) << 3))] = val;
      }
    }
}

// ---------------- output projection: bf16 MFMA, round-3 layout ----------------
__global__ __launch_bounds__(256) void out_gemm_mfma(
    const unsigned short* __restrict__ A, const unsigned short* __restrict__ Bt,
    const float* __restrict__ bias, float* __restrict__ out) {
  __shared__ unsigned short As[128 * 32];
  __shared__ unsigned short Bs[128 * 32];
  const int m0 = blockIdx.x * 128, n0 = blockIdx.y * 128;
  const int tid = threadIdx.x, l = tid & 63, w = tid >> 6;
  const int wm = w >> 1, wn = w & 1;
  const int grp = l >> 4, col = l & 15;
  f32x4 acc[4][4];
#pragma unroll
  for (int mi = 0; mi < 4; ++mi)
#pragma unroll
    for (int ni = 0; ni < 4; ++ni) acc[mi][ni] = (f32x4){0.f, 0.f, 0.f, 0.f};

  for (int k0 = 0; k0 < 1024; k0 += 32) {
    __syncthreads();
#pragma unroll
    for (int i = 0; i < 2; ++i) {
      int seg = i * 256 + w * 64 + l;
      int mr = seg >> 2, kq = seg & 3;
      gload_lds16(A + (size_t)(m0 + mr) * 1024 + k0 + kq * 8,
                  &As[(i * 256 + w * 64) * 8]);
      gload_lds16(Bt + (size_t)(n0 + mr) * 1024 + k0 + kq * 8,
                  &Bs[(i * 256 + w * 64) * 8]);
    }
    __syncthreads();
    short8 af[4], bfv[4];
#pragma unroll
    for (int mi = 0; mi < 4; ++mi)
      af[mi] = *(const short8*)&As[(wm * 64 + mi * 16 + col) * 32 + grp * 8];
#pragma unroll
    for (int ni = 0; ni < 4; ++ni)
      bfv[ni] = *(const short8*)&Bs[(wn * 64 + ni * 16 + col) * 32 + grp * 8];
#pragma unroll
    for (int mi = 0; mi < 4; ++mi)
#pragma unroll
      for (int ni = 0; ni < 4; ++ni)
        acc[mi][ni] = __builtin_amdgcn_mfma_f32_16x16x32_bf16(af[mi], bfv[ni], acc[mi][ni], 0, 0, 0);
  }
  float bv[4];
#pragma unroll
  for (int ni = 0; ni < 4; ++ni) bv[ni] = bias[n0 + wn * 64 + ni * 16 + col];
#pragma unroll
  for (int mi = 0; mi < 4; ++mi)
#pragma unroll
    for (int rr = 0; rr < 4; ++rr) {
      int row = m0 + wm * 64 + mi * 16 + grp * 4 + rr;
#pragma unroll
      for (int ni = 0; ni < 4; ++ni) {
        int c = n0 + wn * 64 + ni * 16 + col;
        out[(size_t)row * 1024 + c] = acc[mi][ni][rr] + bv[ni];
      }
    }
}

// ---------------- G' GEMM: G'[n*1025 + j] = q_n . Er[j] ----------------
__global__ __launch_bounds__(256) void g_gemm2(
    const unsigned short* __restrict__ qb, int bh_base,
    const unsigned short* __restrict__ Er_bf,
    unsigned short* __restrict__ Gp) {
  const int n0 = blockIdx.x * 64;
  const int jq = blockIdx.y;       // 0..3
  const int bhl = blockIdx.z;
  const int bh = bh_base + bhl;
  const int tid = threadIdx.x, l = tid & 63, w = tid >> 6;
  const int grp = l >> 4, col = l & 15;
  const int jw = jq * 256 + w * 64;

  short8 aq[4][2];
#pragma unroll
  for (int rf = 0; rf < 4; ++rf)
#pragma unroll
    for (int dc = 0; dc < 2; ++dc)
      aq[rf][dc] = *(const short8*)(qb + ((size_t)bh * SEQ + n0 + rf * 16 + col) * HD + dc * 32 + grp * 8);

  f32x4 acc[4][4];
#pragma unroll
  for (int rf = 0; rf < 4; ++rf)
#pragma unroll
    for (int cf = 0; cf < 4; ++cf) acc[rf][cf] = (f32x4){0.f, 0.f, 0.f, 0.f};

#pragma unroll
  for (int cf = 0; cf < 4; ++cf)
#pragma unroll
    for (int dc = 0; dc < 2; ++dc) {
      short8 bfrag = *(const short8*)(Er_bf + (size_t)(jw + cf * 16 + col) * HD + dc * 32 + grp * 8);
#pragma unroll
      for (int rf = 0; rf < 4; ++rf)
        acc[rf][cf] = __builtin_amdgcn_mfma_f32_16x16x32_bf16(aq[rf][dc], bfrag, acc[rf][cf], 0, 0, 0);
    }

#pragma unroll
  for (int rf = 0; rf < 4; ++rf)
#pragma unroll
    for (int cf = 0; cf < 4; ++cf)
#pragma unroll
      for (int rr = 0; rr < 4; ++rr) {
        int n = n0 + rf * 16 + grp * 4 + rr;
        int j = jw + cf * 16 + col;
        Gp[((size_t)(bhl * SEQ + n)) * GROW + j] = f2bf(acc[rf][cf][rr]);
      }
}

// ---------------- flash attention: swizzled K/V^T via global_load_lds ----------------
__global__ __launch_bounds__(256) void attn_kernel(
    const unsigned short* __restrict__ qb, const unsigned short* __restrict__ ksw,
    const unsigned short* __restrict__ vtsw, const unsigned short* __restrict__ Gp,
    unsigned short* __restrict__ attn_o, int bh_base) {
  __shared__ __align__(16) unsigned short KsL[64 * 64];
  __shared__ __align__(16) unsigned short VtL[64 * 64];
  __shared__ __align__(16) unsigned short Pw[4][16][72];
  __shared__ __align__(16) unsigned short Band[64][72];

  // XCD-chunked remap: each XCD owns 4 consecutive bh
  const int wg = blockIdx.x + 16 * blockIdx.y;  // 512 wgs
  const int nid = (wg & 7) * 64 + (wg >> 3);
  const int bhl = nid >> 4;
  const int n0 = (nid & 15) * 64;
  const int bh = bh_base + bhl;
  const int b = bh >> 4, h = bh & 15;
  const int tid = threadIdx.x, lane = tid & 63, wq = tid >> 6;
  const int grp = lane >> 4, col = lane & 15;
  const int n0w = n0 + wq * 16;

  short8 aq[2];
#pragma unroll
  for (int dc = 0; dc < 2; ++dc)
    aq[dc] = *(const short8*)(qb + ((size_t)(bh * SEQ + n0w + col)) * HD + dc * 32 + grp * 8);

  f32x4 acco[4];
#pragma unroll
  for (int oc = 0; oc < 4; ++oc) acco[oc] = (f32x4){0.f, 0.f, 0.f, 0.f};
  float mrun[4], lrun[4];
#pragma unroll
  for (int r = 0; r < 4; ++r) { mrun[r] = -INFINITY; lrun[r] = 0.f; }

  const float scale = 0.125f;
  const unsigned short* kbh = ksw + (size_t)bh * SEQ * HD;   // [m][d^((m&7)<<3)]
  const unsigned short* vbh = vtsw + (size_t)bh * HD * SEQ;  // [d][m^((d&7)<<3)]
  const size_t gflat0 = (size_t)(bhl * SEQ + n0) * GROW;

  for (int m0 = 0; m0 < SEQ; m0 += 64) {
    __syncthreads();
    // stage K tile and V^T tile via global_load_lds (linear LDS, swizzle baked in global)
#pragma unroll
    for (int i = 0; i < 2; ++i) {
      int gi = i * 256 + wq * 64 + lane;
      int row = gi >> 3, gc = gi & 7;
      gload_lds16(kbh + (((size_t)(m0 + row)) << 6) + gc * 8,
                  &KsL[(i * 256 + wq * 64) * 8]);
      gload_lds16(vbh + (((size_t)row) << 10) + m0 + gc * 8,
                  &VtL[(i * 256 + wq * 64) * 8]);
    }
    // stage rel band (reg-staged; rows are 16B-aligned by construction)
    for (int idx = tid; idx < 576; idx += 256) {
      int r = idx / 9, seg = idx - r * 9;
      size_t s8 = gflat0 + (size_t)r * GROW + (size_t)(1016 + m0 - (n0 + r));
      short8 gvv = *(const short8*)(Gp + s8 + seg * 8);
      *(short8*)&Band[r][seg * 8] = gvv;
    }
    __syncthreads();
    // QK^T (bk from swizzled KsL)
    f32x4 acc[4];
#pragma unroll
    for (int mc = 0; mc < 4; ++mc) acc[mc] = (f32x4){0.f, 0.f, 0.f, 0.f};
#pragma unroll
    for (int mc = 0; mc < 4; ++mc)
#pragma unroll
      for (int dc = 0; dc < 2; ++dc) {
        short8 bk = *(const short8*)&KsL[(mc * 16 + col) * 64 + (((dc * 4 + grp) ^ (col & 7)) << 3)];
        acc[mc] = __builtin_amdgcn_mfma_f32_16x16x32_bf16(aq[dc], bk, acc[mc], 0, 0, 0);
      }
    // online softmax
#pragma unroll
    for (int r = 0; r < 4; ++r) {
      int dr = wq * 16 + grp * 4 + r;
      int n = n0 + dr;
      float s[4];
#pragma unroll
      for (int mc = 0; mc < 4; ++mc) {
        float g = bf2f(Band[dr][7 + mc * 16 + col]);
        int m = m0 + mc * 16 + col;
        if (m == n + 1) g = 0.f;  // skew's dropped-pad diagonal
        s[mc] = acc[mc][r] * scale + g;
      }
      float mx = fmaxf(fmaxf(s[0], s[1]), fmaxf(s[2], s[3]));
#pragma unroll
      for (int off = 1; off < 16; off <<= 1) mx = fmaxf(mx, __shfl_xor(mx, off));
      float mnew = fmaxf(mrun[r], mx);
      float cr = __expf(mrun[r] - mnew);
      float ls = 0.f;
      float p[4];
#pragma unroll
      for (int mc = 0; mc < 4; ++mc) { p[mc] = __expf(s[mc] - mnew); ls += p[mc]; }
#pragma unroll
      for (int off = 1; off < 16; off <<= 1) ls += __shfl_xor(ls, off);
      lrun[r] = lrun[r] * cr + ls;
      mrun[r] = mnew;
#pragma unroll
      for (int oc = 0; oc < 4; ++oc) acco[oc][r] *= cr;
#pragma unroll
      for (int mc = 0; mc < 4; ++mc) Pw[wq][grp * 4 + r][mc * 16 + col] = f2bf(p[mc]);
    }
    // PV (bv from swizzled VtL)
    short8 ap[2];
#pragma unroll
    for (int kc = 0; kc < 2; ++kc)
      ap[kc] = *(const short8*)&Pw[wq][col][kc * 32 + grp * 8];
#pragma unroll
    for (int oc = 0; oc < 4; ++oc)
#pragma unroll
      for (int kc = 0; kc < 2; ++kc) {
        short8 bv = *(const short8*)&VtL[(oc * 16 + col) * 64 + (((kc * 4 + grp) ^ (col & 7)) << 3)];
        acco[oc] = __builtin_amdgcn_mfma_f32_16x16x32_bf16(ap[kc], bv, acco[oc], 0, 0, 0);
      }
  }
#pragma unroll
  for (int oc = 0; oc < 4; ++oc)
#pragma unroll
    for (int r = 0; r < 4; ++r) {
      int n = n0w + grp * 4 + r;
      int d = oc * 16 + col;
      attn_o[((size_t)(b * SEQ + n)) * CH + h * HD + d] = f2bf(acco[oc][r] / lrun[r]);
    }
}

extern "C" void kernel_launch(void* const* d_in, const int* in_sizes, int n_in,
                              void* d_out, int out_size, void* d_ws, size_t ws_size,
                              hipStream_t stream) {
  const float* x        = (const float*)d_in[0];
  const float* time_emb = (const float*)d_in[1];
  const float* W_qkv    = (const float*)d_in[2];
  const float* b_qkv    = (const float*)d_in[3];
  const float* W_time   = (const float*)d_in[4];
  const float* b_time   = (const float*)d_in[5];
  const float* W_out    = (const float*)d_in[6];
  const float* b_out    = (const float*)d_in[7];
  const float* Er       = (const float*)d_in[8];
  float* out = (float*)d_out;

  char* p = (char*)d_ws;
  float* tqkv = (float*)p;                      p += 98304;
  unsigned short* qb = (unsigned short*)p;      p += 16777216;
  unsigned short* ksw = (unsigned short*)p;     p += 16777216;
  unsigned short* vtsw = (unsigned short*)p;    p += 16777216;
  unsigned short* attn_o = (unsigned short*)p;  p += 16777216;
  unsigned short* Er_bf = (unsigned short*)p;   p += 131072;
  unsigned short* Wout_t = (unsigned short*)p;  p += 2097152;
  unsigned short* x_bf = (unsigned short*)p;               // 16 MB
  unsigned short* Wqkv_t = x_bf + (size_t)8388608;         // 6 MB
  unsigned short* Gp = (unsigned short*)p;                 // 67.2 MB, aliases x_bf (dead)

  er_convert_kernel<<<256, 256, 0, stream>>>(Er, Er_bf);
  time_proj_kernel<<<96, 256, 0, stream>>>(time_emb, W_time, b_time, tqkv);
  convert_bf_kernel<<<4096, 256, 0, stream>>>(x, x_bf, 1048576);
  transpose_bf_kernel<<<dim3(48, 16), 256, 0, stream>>>(W_qkv, Wqkv_t, 1024, 3072);
  transpose_bf_kernel<<<dim3(16, 16), 256, 0, stream>>>(W_out, Wout_t, 1024, 1024);
  qkv_gemm_mfma<<<dim3(64, 24), 256, 0, stream>>>(x_bf, Wqkv_t, b_qkv, tqkv, qb, ksw, vtsw);
  for (int s = 0; s < 4; ++s) {
    int bh_base = s * SLAB_BH;
    g_gemm2<<<dim3(16, 4, SLAB_BH), 256, 0, stream>>>(qb, bh_base, Er_bf, Gp);
    attn_kernel<<<dim3(16, SLAB_BH), 256, 0, stream>>>(qb, ksw, vtsw, Gp, attn_o, bh_base);
  }
  out_gemm_mfma<<<dim3(64, 8), 256, 0, stream>>>(attn_o, Wout_t, b_out, out);
}

// Round 6
// 415.674 us; speedup vs baseline: 1.3283x; 1.0772x over previous
//
#include <hip/hip_runtime.h>
#include <math.h>

typedef __attribute__((ext_vector_type(8))) short short8;
typedef __attribute__((ext_vector_type(8))) unsigned short ushort8;
typedef __attribute__((ext_vector_type(4))) unsigned short us4;
typedef __attribute__((ext_vector_type(4))) float f32x4;

#define NH 16
#define HD 64
#define SEQ 1024
#define NB 8
#define CH 1024
#define TD 256
#define GROW 1025  // flat row stride of G' (the skew trick)

__device__ __forceinline__ unsigned short f2bf(float f) {
  union { float f; unsigned int u; } v; v.f = f;
  unsigned int r = v.u + 0x7FFFu + ((v.u >> 16) & 1u);
  return (unsigned short)(r >> 16);
}
__device__ __forceinline__ float bf2f(unsigned short s) {
  union { unsigned int u; float f; } v; v.u = ((unsigned int)s) << 16;
  return v.f;
}
__device__ __forceinline__ void gload_lds16(const unsigned short* g, unsigned short* l) {
  __builtin_amdgcn_global_load_lds(
      (const __attribute__((address_space(1))) unsigned int*)g,
      (__attribute__((address_space(3))) unsigned int*)l, 16, 0, 0);
}

// ---------------- time projection (fp32) ----------------
__global__ __launch_bounds__(256) void time_proj_kernel(
    const float* __restrict__ time_emb, const float* __restrict__ W_time,
    const float* __restrict__ b_time, float* __restrict__ tqkv) {
  int idx = blockIdx.x * 256 + threadIdx.x;
  if (idx >= NB * 3072) return;
  int b = idx / 3072, c = idx % 3072;
  float s = b_time[c];
  for (int t = 0; t < TD; ++t) s += time_emb[b * TD + t] * W_time[t * 3072 + c];
  tqkv[idx] = s;
}

// ---------------- Er fp32 -> bf16 ----------------
__global__ __launch_bounds__(256) void er_convert_kernel(
    const float* __restrict__ Er, unsigned short* __restrict__ Er_bf) {
  int i = blockIdx.x * 256 + threadIdx.x;
  if (i < SEQ * HD) Er_bf[i] = f2bf(Er[i]);
}

// ---------------- fp32 -> bf16 vector convert ----------------
__global__ __launch_bounds__(256) void convert_bf_kernel(
    const float* __restrict__ in, unsigned short* __restrict__ out, int n8) {
  int i = blockIdx.x * 256 + threadIdx.x;
  if (i >= n8) return;
  float4 a = ((const float4*)in)[2 * i];
  float4 b = ((const float4*)in)[2 * i + 1];
  ushort8 o;
  o[0] = f2bf(a.x); o[1] = f2bf(a.y); o[2] = f2bf(a.z); o[3] = f2bf(a.w);
  o[4] = f2bf(b.x); o[5] = f2bf(b.y); o[6] = f2bf(b.z); o[7] = f2bf(b.w);
  ((ushort8*)out)[i] = o;
}

// ---------------- fp32 W[R][C] -> bf16 Wt[C][R] ----------------
__global__ __launch_bounds__(256) void transpose_bf_kernel(
    const float* __restrict__ W, unsigned short* __restrict__ Wt, int R, int Cc) {
  __shared__ float T[64][65];
  int r0 = blockIdx.y * 64, c0 = blockIdx.x * 64;
  for (int idx = threadIdx.x; idx < 4096; idx += 256) {
    int r = idx >> 6, c = idx & 63;
    T[r][c] = W[(size_t)(r0 + r) * Cc + c0 + c];
  }
  __syncthreads();
  for (int idx = threadIdx.x; idx < 4096; idx += 256) {
    int c = idx >> 6, r = idx & 63;
    Wt[(size_t)(c0 + c) * R + r0 + r] = f2bf(T[r][c]);
  }
}

// ---------------- QKV GEMM: bf16 MFMA ----------------
// q -> qb[bh][n][d]; k -> ksw[bh][n][d ^ ((n&7)<<3)]; v -> vtsw[bh][d][n ^ ((d&7)<<3)]
__global__ __launch_bounds__(256) void qkv_gemm_mfma(
    const unsigned short* __restrict__ A, const unsigned short* __restrict__ Bt,
    const float* __restrict__ bqkv, const float* __restrict__ tqkv,
    unsigned short* __restrict__ qb, unsigned short* __restrict__ ksw,
    unsigned short* __restrict__ vtsw) {
  __shared__ unsigned short As[128 * 32];
  __shared__ unsigned short Bs[128 * 32];
  const int m0 = blockIdx.x * 128, n0 = blockIdx.y * 128;
  const int tid = threadIdx.x, l = tid & 63, w = tid >> 6;
  const int wm = w >> 1, wn = w & 1;
  const int grp = l >> 4, col = l & 15;
  f32x4 acc[4][4];
#pragma unroll
  for (int mi = 0; mi < 4; ++mi)
#pragma unroll
    for (int ni = 0; ni < 4; ++ni) acc[mi][ni] = (f32x4){0.f, 0.f, 0.f, 0.f};

  for (int k0 = 0; k0 < 1024; k0 += 32) {
    __syncthreads();
#pragma unroll
    for (int i = 0; i < 2; ++i) {
      int seg = i * 256 + w * 64 + l;
      int mr = seg >> 2, kq = seg & 3;
      gload_lds16(A + (size_t)(m0 + mr) * 1024 + k0 + kq * 8,
                  &As[(i * 256 + w * 64) * 8]);
      gload_lds16(Bt + (size_t)(n0 + mr) * 1024 + k0 + kq * 8,
                  &Bs[(i * 256 + w * 64) * 8]);
    }
    __syncthreads();
    short8 af[4], bfv[4];
#pragma unroll
    for (int mi = 0; mi < 4; ++mi)
      af[mi] = *(const short8*)&As[(wm * 64 + mi * 16 + col) * 32 + grp * 8];
#pragma unroll
    for (int ni = 0; ni < 4; ++ni)
      bfv[ni] = *(const short8*)&Bs[(wn * 64 + ni * 16 + col) * 32 + grp * 8];
#pragma unroll
    for (int mi = 0; mi < 4; ++mi)
#pragma unroll
      for (int ni = 0; ni < 4; ++ni)
        acc[mi][ni] = __builtin_amdgcn_mfma_f32_16x16x32_bf16(af[mi], bfv[ni], acc[mi][ni], 0, 0, 0);
  }

  const int bidx = m0 >> 10;
  const int which = n0 >> 10;
  float biasv[4];
  int hhv[4], dv[4];
#pragma unroll
  for (int ni = 0; ni < 4; ++ni) {
    int c = n0 + wn * 64 + ni * 16 + col;
    biasv[ni] = bqkv[c] + tqkv[bidx * 3072 + c];
    int cc = c & 1023;
    hhv[ni] = cc >> 6;
    dv[ni] = cc & 63;
  }
  if (which == 2) {
    // V: thread holds 4 consecutive n (rr) per (mi,ni) -> 8B packed store
#pragma unroll
    for (int mi = 0; mi < 4; ++mi) {
      int nn0 = (m0 + wm * 64 + mi * 16 + grp * 4) & 1023;
#pragma unroll
      for (int ni = 0; ni < 4; ++ni) {
        us4 pk;
#pragma unroll
        for (int rr = 0; rr < 4; ++rr) pk[rr] = f2bf(acc[mi][ni][rr] + biasv[ni]);
        size_t bhh = (size_t)(bidx * 16 + hhv[ni]);
        *(us4*)&vtsw[(bhh * 64 + dv[ni]) * 1024 + (nn0 ^ ((dv[ni] & 7) << 3))] = pk;
      }
    }
  } else if (which == 1) {
#pragma unroll
    for (int mi = 0; mi < 4; ++mi)
#pragma unroll
      for (int rr = 0; rr < 4; ++rr) {
        int nn = (m0 + wm * 64 + mi * 16 + grp * 4 + rr) & 1023;
#pragma unroll
        for (int ni = 0; ni < 4; ++ni) {
          size_t bhh = (size_t)(bidx * 16 + hhv[ni]);
          ksw[(bhh * 1024 + nn) * 64 + (dv[ni] ^ ((nn & 7) << 3))] =
              f2bf(acc[mi][ni][rr] + biasv[ni]);
        }
      }
  } else {
#pragma unroll
    for (int mi = 0; mi < 4; ++mi)
#pragma unroll
      for (int rr = 0; rr < 4; ++rr) {
        int nn = (m0 + wm * 64 + mi * 16 + grp * 4 + rr) & 1023;
#pragma unroll
        for (int ni = 0; ni < 4; ++ni) {
          size_t bhh = (size_t)(bidx * 16 + hhv[ni]);
          qb[(bhh * 1024 + nn) * 64 + dv[ni]] = f2bf(acc[mi][ni][rr] + biasv[ni]);
        }
      }
  }
}

// ---------------- output projection: bf16 MFMA ----------------
__global__ __launch_bounds__(256) void out_gemm_mfma(
    const unsigned short* __restrict__ A, const unsigned short* __restrict__ Bt,
    const float* __restrict__ bias, float* __restrict__ out) {
  __shared__ unsigned short As[128 * 32];
  __shared__ unsigned short Bs[128 * 32];
  const int m0 = blockIdx.x * 128, n0 = blockIdx.y * 128;
  const int tid = threadIdx.x, l = tid & 63, w = tid >> 6;
  const int wm = w >> 1, wn = w & 1;
  const int grp = l >> 4, col = l & 15;
  f32x4 acc[4][4];
#pragma unroll
  for (int mi = 0; mi < 4; ++mi)
#pragma unroll
    for (int ni = 0; ni < 4; ++ni) acc[mi][ni] = (f32x4){0.f, 0.f, 0.f, 0.f};

  for (int k0 = 0; k0 < 1024; k0 += 32) {
    __syncthreads();
#pragma unroll
    for (int i = 0; i < 2; ++i) {
      int seg = i * 256 + w * 64 + l;
      int mr = seg >> 2, kq = seg & 3;
      gload_lds16(A + (size_t)(m0 + mr) * 1024 + k0 + kq * 8,
                  &As[(i * 256 + w * 64) * 8]);
      gload_lds16(Bt + (size_t)(n0 + mr) * 1024 + k0 + kq * 8,
                  &Bs[(i * 256 + w * 64) * 8]);
    }
    __syncthreads();
    short8 af[4], bfv[4];
#pragma unroll
    for (int mi = 0; mi < 4; ++mi)
      af[mi] = *(const short8*)&As[(wm * 64 + mi * 16 + col) * 32 + grp * 8];
#pragma unroll
    for (int ni = 0; ni < 4; ++ni)
      bfv[ni] = *(const short8*)&Bs[(wn * 64 + ni * 16 + col) * 32 + grp * 8];
#pragma unroll
    for (int mi = 0; mi < 4; ++mi)
#pragma unroll
      for (int ni = 0; ni < 4; ++ni)
        acc[mi][ni] = __builtin_amdgcn_mfma_f32_16x16x32_bf16(af[mi], bfv[ni], acc[mi][ni], 0, 0, 0);
  }
  float bv[4];
#pragma unroll
  for (int ni = 0; ni < 4; ++ni) bv[ni] = bias[n0 + wn * 64 + ni * 16 + col];
#pragma unroll
  for (int mi = 0; mi < 4; ++mi)
#pragma unroll
    for (int rr = 0; rr < 4; ++rr) {
      int row = m0 + wm * 64 + mi * 16 + grp * 4 + rr;
#pragma unroll
      for (int ni = 0; ni < 4; ++ni) {
        int c = n0 + wn * 64 + ni * 16 + col;
        out[(size_t)row * 1024 + c] = acc[mi][ni][rr] + bv[ni];
      }
    }
}

// ---------------- G' GEMM: G'[n*1025 + j] = q_n . Er[j] ----------------
__global__ __launch_bounds__(256) void g_gemm2(
    const unsigned short* __restrict__ qb, int bh_base,
    const unsigned short* __restrict__ Er_bf,
    unsigned short* __restrict__ Gp) {
  const int n0 = blockIdx.x * 64;
  const int jq = blockIdx.y;       // 0..3
  const int bhl = blockIdx.z;
  const int bh = bh_base + bhl;
  const int tid = threadIdx.x, l = tid & 63, w = tid >> 6;
  const int grp = l >> 4, col = l & 15;
  const int jw = jq * 256 + w * 64;

  short8 aq[4][2];
#pragma unroll
  for (int rf = 0; rf < 4; ++rf)
#pragma unroll
    for (int dc = 0; dc < 2; ++dc)
      aq[rf][dc] = *(const short8*)(qb + ((size_t)bh * SEQ + n0 + rf * 16 + col) * HD + dc * 32 + grp * 8);

  f32x4 acc[4][4];
#pragma unroll
  for (int rf = 0; rf < 4; ++rf)
#pragma unroll
    for (int cf = 0; cf < 4; ++cf) acc[rf][cf] = (f32x4){0.f, 0.f, 0.f, 0.f};

#pragma unroll
  for (int cf = 0; cf < 4; ++cf)
#pragma unroll
    for (int dc = 0; dc < 2; ++dc) {
      short8 bfrag = *(const short8*)(Er_bf + (size_t)(jw + cf * 16 + col) * HD + dc * 32 + grp * 8);
#pragma unroll
      for (int rf = 0; rf < 4; ++rf)
        acc[rf][cf] = __builtin_amdgcn_mfma_f32_16x16x32_bf16(aq[rf][dc], bfrag, acc[rf][cf], 0, 0, 0);
    }

#pragma unroll
  for (int rf = 0; rf < 4; ++rf)
#pragma unroll
    for (int cf = 0; cf < 4; ++cf)
#pragma unroll
      for (int rr = 0; rr < 4; ++rr) {
        int n = n0 + rf * 16 + grp * 4 + rr;
        int j = jw + cf * 16 + col;
        Gp[((size_t)(bhl * SEQ + n)) * GROW + j] = f2bf(acc[rf][cf][rr]);
      }
}

// ---------------- flash attention ----------------
__global__ __launch_bounds__(256) void attn_kernel(
    const unsigned short* __restrict__ qb, const unsigned short* __restrict__ ksw,
    const unsigned short* __restrict__ vtsw, const unsigned short* __restrict__ Gp,
    unsigned short* __restrict__ attn_o, int bh_base) {
  __shared__ __align__(16) unsigned short KsL[64 * 64];
  __shared__ __align__(16) unsigned short VtL[64 * 64];
  __shared__ __align__(16) unsigned short Pw[4][16][72];
  __shared__ __align__(16) unsigned short Band[64][72];

  // XCD-chunked remap: contiguous bh ranges per XCD
  const int wg = blockIdx.x + 16 * blockIdx.y;
  const int chunk = 2 * gridDim.y;  // nwg/8
  const int nid = (wg & 7) * chunk + (wg >> 3);
  const int bhl = nid >> 4;
  const int n0 = (nid & 15) * 64;
  const int bh = bh_base + bhl;
  const int b = bh >> 4, h = bh & 15;
  const int tid = threadIdx.x, lane = tid & 63, wq = tid >> 6;
  const int grp = lane >> 4, col = lane & 15;
  const int n0w = n0 + wq * 16;

  short8 aq[2];
#pragma unroll
  for (int dc = 0; dc < 2; ++dc)
    aq[dc] = *(const short8*)(qb + ((size_t)(bh * SEQ + n0w + col)) * HD + dc * 32 + grp * 8);

  f32x4 acco[4];
#pragma unroll
  for (int oc = 0; oc < 4; ++oc) acco[oc] = (f32x4){0.f, 0.f, 0.f, 0.f};
  float mrun[4], lrun[4];
#pragma unroll
  for (int r = 0; r < 4; ++r) { mrun[r] = -INFINITY; lrun[r] = 0.f; }

  const float scale = 0.125f;
  const unsigned short* kbh = ksw + (size_t)bh * SEQ * HD;   // [m][d^((m&7)<<3)]
  const unsigned short* vbh = vtsw + (size_t)bh * HD * SEQ;  // [d][m^((d&7)<<3)]
  // flat band base: pos(r,m0) = gflat0 + (1016 + m0 - n0) + r*1024  (since r*1025 - r = r*1024)
  const unsigned short* gbase = Gp + (size_t)(bhl * SEQ + n0) * GROW + (1016 - n0);

  for (int m0 = 0; m0 < SEQ; m0 += 64) {
    __syncthreads();
    // stage K tile and V^T tile (swizzle baked into global layout)
#pragma unroll
    for (int i = 0; i < 2; ++i) {
      int gi = i * 256 + wq * 64 + lane;
      int row = gi >> 3, gc = gi & 7;
      gload_lds16(kbh + (((size_t)(m0 + row)) << 6) + gc * 8,
                  &KsL[(i * 256 + wq * 64) * 8]);
      gload_lds16(vbh + (((size_t)row) << 10) + m0 + gc * 8,
                  &VtL[(i * 256 + wq * 64) * 8]);
    }
    // stage rel band directly via global_load_lds: Band rows are 9 granules, linear
    {
      const unsigned short* gsrc = gbase + m0;
      unsigned short* bdst = &Band[0][0];
      const int g0 = wq * 144;  // wave wq owns rows [wq*16, wq*16+16) = 144 granules
#pragma unroll
      for (int it = 0; it < 2; ++it) {
        int g = g0 + it * 64 + lane;
        int r = g / 9, seg = g - r * 9;
        gload_lds16(gsrc + r * 1024 + seg * 8, bdst + (g0 + it * 64) * 8);
      }
      if (lane < 16) {
        int g = g0 + 128 + lane;
        int r = g / 9, seg = g - r * 9;
        gload_lds16(gsrc + r * 1024 + seg * 8, bdst + (g0 + 128) * 8);
      }
    }
    __syncthreads();
    // QK^T
    f32x4 acc[4];
#pragma unroll
    for (int mc = 0; mc < 4; ++mc) acc[mc] = (f32x4){0.f, 0.f, 0.f, 0.f};
#pragma unroll
    for (int mc = 0; mc < 4; ++mc)
#pragma unroll
      for (int dc = 0; dc < 2; ++dc) {
        short8 bk = *(const short8*)&KsL[(mc * 16 + col) * 64 + (((dc * 4 + grp) ^ (col & 7)) << 3)];
        acc[mc] = __builtin_amdgcn_mfma_f32_16x16x32_bf16(aq[dc], bk, acc[mc], 0, 0, 0);
      }
    // online softmax (exact defer: skip rescale when max doesn't grow)
#pragma unroll
    for (int r = 0; r < 4; ++r) {
      int dr = wq * 16 + grp * 4 + r;
      int n = n0 + dr;
      float s[4];
#pragma unroll
      for (int mc = 0; mc < 4; ++mc) {
        float g = bf2f(Band[dr][7 + mc * 16 + col]);
        int m = m0 + mc * 16 + col;
        if (m == n + 1) g = 0.f;  // skew's dropped-pad diagonal (unwritten hole)
        s[mc] = acc[mc][r] * scale + g;
      }
      float mx = fmaxf(fmaxf(s[0], s[1]), fmaxf(s[2], s[3]));
#pragma unroll
      for (int off = 1; off < 16; off <<= 1) mx = fmaxf(mx, __shfl_xor(mx, off));
      if (mx > mrun[r]) {
        float cr = __expf(mrun[r] - mx);
        mrun[r] = mx;
        lrun[r] *= cr;
#pragma unroll
        for (int oc = 0; oc < 4; ++oc) acco[oc][r] *= cr;
      }
      float ls = 0.f;
      float p[4];
#pragma unroll
      for (int mc = 0; mc < 4; ++mc) { p[mc] = __expf(s[mc] - mrun[r]); ls += p[mc]; }
#pragma unroll
      for (int off = 1; off < 16; off <<= 1) ls += __shfl_xor(ls, off);
      lrun[r] += ls;
#pragma unroll
      for (int mc = 0; mc < 4; ++mc) Pw[wq][grp * 4 + r][mc * 16 + col] = f2bf(p[mc]);
    }
    // PV
    short8 ap[2];
#pragma unroll
    for (int kc = 0; kc < 2; ++kc)
      ap[kc] = *(const short8*)&Pw[wq][col][kc * 32 + grp * 8];
#pragma unroll
    for (int oc = 0; oc < 4; ++oc)
#pragma unroll
      for (int kc = 0; kc < 2; ++kc) {
        short8 bv = *(const short8*)&VtL[(oc * 16 + col) * 64 + (((kc * 4 + grp) ^ (col & 7)) << 3)];
        acco[oc] = __builtin_amdgcn_mfma_f32_16x16x32_bf16(ap[kc], bv, acco[oc], 0, 0, 0);
      }
  }
#pragma unroll
  for (int oc = 0; oc < 4; ++oc)
#pragma unroll
    for (int r = 0; r < 4; ++r) {
      int n = n0w + grp * 4 + r;
      int d = oc * 16 + col;
      attn_o[((size_t)(b * SEQ + n)) * CH + h * HD + d] = f2bf(acco[oc][r] / lrun[r]);
    }
}

extern "C" void kernel_launch(void* const* d_in, const int* in_sizes, int n_in,
                              void* d_out, int out_size, void* d_ws, size_t ws_size,
                              hipStream_t stream) {
  const float* x        = (const float*)d_in[0];
  const float* time_emb = (const float*)d_in[1];
  const float* W_qkv    = (const float*)d_in[2];
  const float* b_qkv    = (const float*)d_in[3];
  const float* W_time   = (const float*)d_in[4];
  const float* b_time   = (const float*)d_in[5];
  const float* W_out    = (const float*)d_in[6];
  const float* b_out    = (const float*)d_in[7];
  const float* Er       = (const float*)d_in[8];
  float* out = (float*)d_out;

  char* p = (char*)d_ws;
  float* tqkv = (float*)p;                      p += 98304;
  unsigned short* qb = (unsigned short*)p;      p += 16777216;
  unsigned short* ksw = (unsigned short*)p;     p += 16777216;
  unsigned short* vtsw = (unsigned short*)p;    p += 16777216;
  unsigned short* attn_o = (unsigned short*)p;  p += 16777216;
  unsigned short* Er_bf = (unsigned short*)p;   p += 131072;
  unsigned short* Wout_t = (unsigned short*)p;  p += 2097152;
  unsigned short* x_bf = (unsigned short*)p;               // 16 MB (prep, then dead)
  unsigned short* Wqkv_t = x_bf + (size_t)8388608;         // 6 MB (prep, then dead)
  unsigned short* Gp = (unsigned short*)p;                 // slab Gp, aliases prep region

  // pick slab size by available workspace (deterministic in ws_size)
  size_t fixed = (size_t)(p - (char*)d_ws);
  int slab_bh = (ws_size >= fixed + (size_t)64 * 2099200) ? 64 : 32;
  int nslab = 128 / slab_bh;

  er_convert_kernel<<<256, 256, 0, stream>>>(Er, Er_bf);
  time_proj_kernel<<<96, 256, 0, stream>>>(time_emb, W_time, b_time, tqkv);
  convert_bf_kernel<<<4096, 256, 0, stream>>>(x, x_bf, 1048576);
  transpose_bf_kernel<<<dim3(48, 16), 256, 0, stream>>>(W_qkv, Wqkv_t, 1024, 3072);
  transpose_bf_kernel<<<dim3(16, 16), 256, 0, stream>>>(W_out, Wout_t, 1024, 1024);
  qkv_gemm_mfma<<<dim3(64, 24), 256, 0, stream>>>(x_bf, Wqkv_t, b_qkv, tqkv, qb, ksw, vtsw);
  for (int s = 0; s < nslab; ++s) {
    int bh_base = s * slab_bh;
    g_gemm2<<<dim3(16, 4, slab_bh), 256, 0, stream>>>(qb, bh_base, Er_bf, Gp);
    attn_kernel<<<dim3(16, slab_bh), 256, 0, stream>>>(qb, ksw, vtsw, Gp, attn_o, bh_base);
  }
  out_gemm_mfma<<<dim3(64, 8), 256, 0, stream>>>(attn_o, Wout_t, b_out, out);
}

// Round 7
// 397.935 us; speedup vs baseline: 1.3875x; 1.0446x over previous
//
#include <hip/hip_runtime.h>
#include <math.h>

typedef __attribute__((ext_vector_type(8))) short short8;
typedef __attribute__((ext_vector_type(8))) unsigned short ushort8;
typedef __attribute__((ext_vector_type(4))) unsigned short us4;
typedef __attribute__((ext_vector_type(4))) float f32x4;

#define NH 16
#define HD 64
#define SEQ 1024
#define NB 8
#define CH 1024
#define TD 256
#define GROW 1025  // flat row stride of G' (the skew trick)
#define LOG2E 1.4426950408889634f

__device__ __forceinline__ unsigned short f2bf(float f) {
  union { float f; unsigned int u; } v; v.f = f;
  unsigned int r = v.u + 0x7FFFu + ((v.u >> 16) & 1u);
  return (unsigned short)(r >> 16);
}
__device__ __forceinline__ float bf2f(unsigned short s) {
  union { unsigned int u; float f; } v; v.u = ((unsigned int)s) << 16;
  return v.f;
}
__device__ __forceinline__ float hexp2(float x) {
  float r;
  asm("v_exp_f32 %0, %1" : "=v"(r) : "v"(x));
  return r;
}
__device__ __forceinline__ void gload_lds16(const unsigned short* g, unsigned short* l) {
  __builtin_amdgcn_global_load_lds(
      (const __attribute__((address_space(1))) unsigned int*)g,
      (__attribute__((address_space(3))) unsigned int*)l, 16, 0, 0);
}

// ---------------- time projection (fp32) ----------------
__global__ __launch_bounds__(256) void time_proj_kernel(
    const float* __restrict__ time_emb, const float* __restrict__ W_time,
    const float* __restrict__ b_time, float* __restrict__ tqkv) {
  int idx = blockIdx.x * 256 + threadIdx.x;
  if (idx >= NB * 3072) return;
  int b = idx / 3072, c = idx % 3072;
  float s = b_time[c];
  for (int t = 0; t < TD; ++t) s += time_emb[b * TD + t] * W_time[t * 3072 + c];
  tqkv[idx] = s;
}

// ---------------- Er fp32 -> bf16, scaled by log2e ----------------
__global__ __launch_bounds__(256) void er_convert_kernel(
    const float* __restrict__ Er, unsigned short* __restrict__ Er_bf) {
  int i = blockIdx.x * 256 + threadIdx.x;
  if (i < SEQ * HD) Er_bf[i] = f2bf(Er[i] * LOG2E);
}

// ---------------- fp32 -> bf16 vector convert ----------------
__global__ __launch_bounds__(256) void convert_bf_kernel(
    const float* __restrict__ in, unsigned short* __restrict__ out, int n8) {
  int i = blockIdx.x * 256 + threadIdx.x;
  if (i >= n8) return;
  float4 a = ((const float4*)in)[2 * i];
  float4 b = ((const float4*)in)[2 * i + 1];
  ushort8 o;
  o[0] = f2bf(a.x); o[1] = f2bf(a.y); o[2] = f2bf(a.z); o[3] = f2bf(a.w);
  o[4] = f2bf(b.x); o[5] = f2bf(b.y); o[6] = f2bf(b.z); o[7] = f2bf(b.w);
  ((ushort8*)out)[i] = o;
}

// ---------------- fp32 W[R][C] -> bf16 Wt[C][R] ----------------
__global__ __launch_bounds__(256) void transpose_bf_kernel(
    const float* __restrict__ W, unsigned short* __restrict__ Wt, int R, int Cc) {
  __shared__ float T[64][65];
  int r0 = blockIdx.y * 64, c0 = blockIdx.x * 64;
  for (int idx = threadIdx.x; idx < 4096; idx += 256) {
    int r = idx >> 6, c = idx & 63;
    T[r][c] = W[(size_t)(r0 + r) * Cc + c0 + c];
  }
  __syncthreads();
  for (int idx = threadIdx.x; idx < 4096; idx += 256) {
    int c = idx >> 6, r = idx & 63;
    Wt[(size_t)(c0 + c) * R + r0 + r] = f2bf(T[r][c]);
  }
}

// ---------------- QKV GEMM: bf16 MFMA ----------------
// q -> qb[bh][n][d]
// k -> ksw[bh][n][d ^ ((n&7)<<3)]
// v -> vtsw[bh][d][tile(n) + swz(pi(n&63))], pi(s)=(s&15)*4+(s>>4), swz: granule^=(d&7)
__global__ __launch_bounds__(256) void qkv_gemm_mfma(
    const unsigned short* __restrict__ A, const unsigned short* __restrict__ Bt,
    const float* __restrict__ bqkv, const float* __restrict__ tqkv,
    unsigned short* __restrict__ qb, unsigned short* __restrict__ ksw,
    unsigned short* __restrict__ vtsw) {
  __shared__ unsigned short As[128 * 32];
  __shared__ unsigned short Bs[128 * 32];
  const int m0 = blockIdx.x * 128, n0 = blockIdx.y * 128;
  const int tid = threadIdx.x, l = tid & 63, w = tid >> 6;
  const int wm = w >> 1, wn = w & 1;
  const int grp = l >> 4, col = l & 15;
  f32x4 acc[4][4];
#pragma unroll
  for (int mi = 0; mi < 4; ++mi)
#pragma unroll
    for (int ni = 0; ni < 4; ++ni) acc[mi][ni] = (f32x4){0.f, 0.f, 0.f, 0.f};

  for (int k0 = 0; k0 < 1024; k0 += 32) {
    __syncthreads();
#pragma unroll
    for (int i = 0; i < 2; ++i) {
      int seg = i * 256 + w * 64 + l;
      int mr = seg >> 2, kq = seg & 3;
      gload_lds16(A + (size_t)(m0 + mr) * 1024 + k0 + kq * 8,
                  &As[(i * 256 + w * 64) * 8]);
      gload_lds16(Bt + (size_t)(n0 + mr) * 1024 + k0 + kq * 8,
                  &Bs[(i * 256 + w * 64) * 8]);
    }
    __syncthreads();
    short8 af[4], bfv[4];
#pragma unroll
    for (int mi = 0; mi < 4; ++mi)
      af[mi] = *(const short8*)&As[(wm * 64 + mi * 16 + col) * 32 + grp * 8];
#pragma unroll
    for (int ni = 0; ni < 4; ++ni)
      bfv[ni] = *(const short8*)&Bs[(wn * 64 + ni * 16 + col) * 32 + grp * 8];
#pragma unroll
    for (int mi = 0; mi < 4; ++mi)
#pragma unroll
      for (int ni = 0; ni < 4; ++ni)
        acc[mi][ni] = __builtin_amdgcn_mfma_f32_16x16x32_bf16(af[mi], bfv[ni], acc[mi][ni], 0, 0, 0);
  }

  const int bidx = m0 >> 10;
  const int which = n0 >> 10;
  float biasv[4];
  int hhv[4], dv[4];
#pragma unroll
  for (int ni = 0; ni < 4; ++ni) {
    int c = n0 + wn * 64 + ni * 16 + col;
    biasv[ni] = bqkv[c] + tqkv[bidx * 3072 + c];
    int cc = c & 1023;
    hhv[ni] = cc >> 6;
    dv[ni] = cc & 63;
  }
  if (which == 2) {
    // V: pack across mi (n stride 16) -> contiguous pi-slots; one us4 store each
    int t = (m0 & 1023) + wm * 64;  // 64-aligned tile base of n
#pragma unroll
    for (int ni = 0; ni < 4; ++ni) {
      size_t rowb = ((size_t)(bidx * 16 + hhv[ni]) * 64 + dv[ni]) * 1024;
      int swz = (dv[ni] & 7) << 3;
#pragma unroll
      for (int rr = 0; rr < 4; ++rr) {
        int kbase = (grp * 4 + rr) * 4;  // pi((n&15)) * 4, mi fills +0..3
        int colix = t + ((kbase & ~7) ^ swz) + (kbase & 7);
        us4 pk;
#pragma unroll
        for (int mi = 0; mi < 4; ++mi) pk[mi] = f2bf(acc[mi][ni][rr] + biasv[ni]);
        *(us4*)&vtsw[rowb + colix] = pk;
      }
    }
  } else if (which == 1) {
#pragma unroll
    for (int mi = 0; mi < 4; ++mi)
#pragma unroll
      for (int rr = 0; rr < 4; ++rr) {
        int nn = (m0 + wm * 64 + mi * 16 + grp * 4 + rr) & 1023;
#pragma unroll
        for (int ni = 0; ni < 4; ++ni) {
          size_t bhh = (size_t)(bidx * 16 + hhv[ni]);
          ksw[(bhh * 1024 + nn) * 64 + (dv[ni] ^ ((nn & 7) << 3))] =
              f2bf(acc[mi][ni][rr] + biasv[ni]);
        }
      }
  } else {
#pragma unroll
    for (int mi = 0; mi < 4; ++mi)
#pragma unroll
      for (int rr = 0; rr < 4; ++rr) {
        int nn = (m0 + wm * 64 + mi * 16 + grp * 4 + rr) & 1023;
#pragma unroll
        for (int ni = 0; ni < 4; ++ni) {
          size_t bhh = (size_t)(bidx * 16 + hhv[ni]);
          qb[(bhh * 1024 + nn) * 64 + dv[ni]] = f2bf(acc[mi][ni][rr] + biasv[ni]);
        }
      }
  }
}

// ---------------- output projection: bf16 MFMA ----------------
__global__ __launch_bounds__(256) void out_gemm_mfma(
    const unsigned short* __restrict__ A, const unsigned short* __restrict__ Bt,
    const float* __restrict__ bias, float* __restrict__ out) {
  __shared__ unsigned short As[128 * 32];
  __shared__ unsigned short Bs[128 * 32];
  const int m0 = blockIdx.x * 128, n0 = blockIdx.y * 128;
  const int tid = threadIdx.x, l = tid & 63, w = tid >> 6;
  const int wm = w >> 1, wn = w & 1;
  const int grp = l >> 4, col = l & 15;
  f32x4 acc[4][4];
#pragma unroll
  for (int mi = 0; mi < 4; ++mi)
#pragma unroll
    for (int ni = 0; ni < 4; ++ni) acc[mi][ni] = (f32x4){0.f, 0.f, 0.f, 0.f};

  for (int k0 = 0; k0 < 1024; k0 += 32) {
    __syncthreads();
#pragma unroll
    for (int i = 0; i < 2; ++i) {
      int seg = i * 256 + w * 64 + l;
      int mr = seg >> 2, kq = seg & 3;
      gload_lds16(A + (size_t)(m0 + mr) * 1024 + k0 + kq * 8,
                  &As[(i * 256 + w * 64) * 8]);
      gload_lds16(Bt + (size_t)(n0 + mr) * 1024 + k0 + kq * 8,
                  &Bs[(i * 256 + w * 64) * 8]);
    }
    __syncthreads();
    short8 af[4], bfv[4];
#pragma unroll
    for (int mi = 0; mi < 4; ++mi)
      af[mi] = *(const short8*)&As[(wm * 64 + mi * 16 + col) * 32 + grp * 8];
#pragma unroll
    for (int ni = 0; ni < 4; ++ni)
      bfv[ni] = *(const short8*)&Bs[(wn * 64 + ni * 16 + col) * 32 + grp * 8];
#pragma unroll
    for (int mi = 0; mi < 4; ++mi)
#pragma unroll
      for (int ni = 0; ni < 4; ++ni)
        acc[mi][ni] = __builtin_amdgcn_mfma_f32_16x16x32_bf16(af[mi], bfv[ni], acc[mi][ni], 0, 0, 0);
  }
  float bv[4];
#pragma unroll
  for (int ni = 0; ni < 4; ++ni) bv[ni] = bias[n0 + wn * 64 + ni * 16 + col];
#pragma unroll
  for (int mi = 0; mi < 4; ++mi)
#pragma unroll
    for (int rr = 0; rr < 4; ++rr) {
      int row = m0 + wm * 64 + mi * 16 + grp * 4 + rr;
#pragma unroll
      for (int ni = 0; ni < 4; ++ni) {
        int c = n0 + wn * 64 + ni * 16 + col;
        out[(size_t)row * 1024 + c] = acc[mi][ni][rr] + bv[ni];
      }
    }
}

// ---------------- G' GEMM: G'[n*1025 + j] = q_n . Er'[j]; zero the skew hole ----------------
__global__ __launch_bounds__(256) void g_gemm2(
    const unsigned short* __restrict__ qb, int bh_base,
    const unsigned short* __restrict__ Er_bf,
    unsigned short* __restrict__ Gp) {
  const int n0 = blockIdx.x * 64;
  const int jq = blockIdx.y;       // 0..3
  const int bhl = blockIdx.z;
  const int bh = bh_base + bhl;
  const int tid = threadIdx.x, l = tid & 63, w = tid >> 6;
  const int grp = l >> 4, col = l & 15;
  const int jw = jq * 256 + w * 64;

  short8 aq[4][2];
#pragma unroll
  for (int rf = 0; rf < 4; ++rf)
#pragma unroll
    for (int dc = 0; dc < 2; ++dc)
      aq[rf][dc] = *(const short8*)(qb + ((size_t)bh * SEQ + n0 + rf * 16 + col) * HD + dc * 32 + grp * 8);

  f32x4 acc[4][4];
#pragma unroll
  for (int rf = 0; rf < 4; ++rf)
#pragma unroll
    for (int cf = 0; cf < 4; ++cf) acc[rf][cf] = (f32x4){0.f, 0.f, 0.f, 0.f};

#pragma unroll
  for (int cf = 0; cf < 4; ++cf)
#pragma unroll
    for (int dc = 0; dc < 2; ++dc) {
      short8 bfrag = *(const short8*)(Er_bf + (size_t)(jw + cf * 16 + col) * HD + dc * 32 + grp * 8);
#pragma unroll
      for (int rf = 0; rf < 4; ++rf)
        acc[rf][cf] = __builtin_amdgcn_mfma_f32_16x16x32_bf16(aq[rf][dc], bfrag, acc[rf][cf], 0, 0, 0);
    }

#pragma unroll
  for (int rf = 0; rf < 4; ++rf)
#pragma unroll
    for (int cf = 0; cf < 4; ++cf)
#pragma unroll
      for (int rr = 0; rr < 4; ++rr) {
        int n = n0 + rf * 16 + grp * 4 + rr;
        int j = jw + cf * 16 + col;
        Gp[((size_t)(bhl * SEQ + n)) * GROW + j] = f2bf(acc[rf][cf][rr]);
      }
  // zero the skew's dropped-pad hole (flat n*1025+1024) so attn needs no mask
  if (jq == 3 && tid < 64) {
    int n = n0 + tid;
    Gp[((size_t)(bhl * SEQ + n)) * GROW + 1024] = 0;
  }
}

// ---------------- flash attention ----------------
__global__ __launch_bounds__(256) void attn_kernel(
    const unsigned short* __restrict__ qb, const unsigned short* __restrict__ ksw,
    const unsigned short* __restrict__ vtsw, const unsigned short* __restrict__ Gp,
    unsigned short* __restrict__ attn_o, int bh_base) {
  __shared__ __align__(16) unsigned short KsL[64 * 64];
  __shared__ __align__(16) unsigned short VtL[64 * 64];
  __shared__ __align__(16) unsigned short Pw[4][16][72];
  __shared__ __align__(16) unsigned short Band[64][72];

  // XCD-chunked remap: contiguous bh ranges per XCD
  const int wg = blockIdx.x + 16 * blockIdx.y;
  const int chunk = 2 * gridDim.y;  // nwg/8
  const int nid = (wg & 7) * chunk + (wg >> 3);
  const int bhl = nid >> 4;
  const int n0 = (nid & 15) * 64;
  const int bh = bh_base + bhl;
  const int b = bh >> 4, h = bh & 15;
  const int tid = threadIdx.x, lane = tid & 63, wq = tid >> 6;
  const int grp = lane >> 4, col = lane & 15;
  const int n0w = n0 + wq * 16;

  short8 aq[2];
#pragma unroll
  for (int dc = 0; dc < 2; ++dc)
    aq[dc] = *(const short8*)(qb + ((size_t)(bh * SEQ + n0w + col)) * HD + dc * 32 + grp * 8);

  f32x4 acco[4];
#pragma unroll
  for (int oc = 0; oc < 4; ++oc) acco[oc] = (f32x4){0.f, 0.f, 0.f, 0.f};
  float mrun[4], lrun[4];
#pragma unroll
  for (int r = 0; r < 4; ++r) { mrun[r] = -INFINITY; lrun[r] = 0.f; }

  const float scale2 = 0.125f * LOG2E;  // log2-domain scale (Er carries log2e)
  const unsigned short* kbh = ksw + (size_t)bh * SEQ * HD;   // [m][d^((m&7)<<3)]
  const unsigned short* vbh = vtsw + (size_t)bh * HD * SEQ;  // [d][tile+swz(pi)]
  const unsigned short* gbase = Gp + (size_t)(bhl * SEQ + n0) * GROW + (1016 - n0);

  for (int m0 = 0; m0 < SEQ; m0 += 64) {
    __syncthreads();
    // stage K tile and V^T tile (swizzle baked into global layout)
#pragma unroll
    for (int i = 0; i < 2; ++i) {
      int gi = i * 256 + wq * 64 + lane;
      int row = gi >> 3, gc = gi & 7;
      gload_lds16(kbh + (((size_t)(m0 + row)) << 6) + gc * 8,
                  &KsL[(i * 256 + wq * 64) * 8]);
      gload_lds16(vbh + (((size_t)row) << 10) + m0 + gc * 8,
                  &VtL[(i * 256 + wq * 64) * 8]);
    }
    // stage rel band via global_load_lds
    {
      const unsigned short* gsrc = gbase + m0;
      unsigned short* bdst = &Band[0][0];
      const int g0 = wq * 144;
#pragma unroll
      for (int it = 0; it < 2; ++it) {
        int g = g0 + it * 64 + lane;
        int r = g / 9, seg = g - r * 9;
        gload_lds16(gsrc + r * 1024 + seg * 8, bdst + (g0 + it * 64) * 8);
      }
      if (lane < 16) {
        int g = g0 + 128 + lane;
        int r = g / 9, seg = g - r * 9;
        gload_lds16(gsrc + r * 1024 + seg * 8, bdst + (g0 + 128) * 8);
      }
    }
    __syncthreads();
    // QK^T
    f32x4 acc[4];
#pragma unroll
    for (int mc = 0; mc < 4; ++mc) acc[mc] = (f32x4){0.f, 0.f, 0.f, 0.f};
#pragma unroll
    for (int mc = 0; mc < 4; ++mc)
#pragma unroll
      for (int dc = 0; dc < 2; ++dc) {
        short8 bk = *(const short8*)&KsL[(mc * 16 + col) * 64 + (((dc * 4 + grp) ^ (col & 7)) << 3)];
        acc[mc] = __builtin_amdgcn_mfma_f32_16x16x32_bf16(aq[dc], bk, acc[mc], 0, 0, 0);
      }
    // online softmax in log2 domain (exact defer-rescale)
#pragma unroll
    for (int r = 0; r < 4; ++r) {
      int dr = wq * 16 + grp * 4 + r;
      float s[4];
#pragma unroll
      for (int mc = 0; mc < 4; ++mc)
        s[mc] = fmaf(acc[mc][r], scale2, bf2f(Band[dr][7 + mc * 16 + col]));
      float mx = fmaxf(fmaxf(s[0], s[1]), fmaxf(s[2], s[3]));
#pragma unroll
      for (int off = 1; off < 16; off <<= 1) mx = fmaxf(mx, __shfl_xor(mx, off));
      if (mx > mrun[r]) {
        float cr = hexp2(mrun[r] - mx);
        mrun[r] = mx;
        lrun[r] *= cr;
#pragma unroll
        for (int oc = 0; oc < 4; ++oc) acco[oc][r] *= cr;
      }
      float p0 = hexp2(s[0] - mrun[r]);
      float p1 = hexp2(s[1] - mrun[r]);
      float p2 = hexp2(s[2] - mrun[r]);
      float p3 = hexp2(s[3] - mrun[r]);
      float ls = (p0 + p1) + (p2 + p3);
#pragma unroll
      for (int off = 1; off < 16; off <<= 1) ls += __shfl_xor(ls, off);
      lrun[r] += ls;
      unsigned int r01, r23;
      asm("v_cvt_pk_bf16_f32 %0, %1, %2" : "=v"(r01) : "v"(p0), "v"(p1));
      asm("v_cvt_pk_bf16_f32 %0, %1, %2" : "=v"(r23) : "v"(p2), "v"(p3));
      unsigned long long pk = (unsigned long long)r01 | ((unsigned long long)r23 << 32);
      *(unsigned long long*)&Pw[wq][grp * 4 + r][col * 4] = pk;  // pi-slots col*4+mc
    }
    // PV (k-dim in pi-order on BOTH operands)
    short8 ap[2];
#pragma unroll
    for (int kc = 0; kc < 2; ++kc)
      ap[kc] = *(const short8*)&Pw[wq][col][kc * 32 + grp * 8];
#pragma unroll
    for (int oc = 0; oc < 4; ++oc)
#pragma unroll
      for (int kc = 0; kc < 2; ++kc) {
        short8 bv = *(const short8*)&VtL[(oc * 16 + col) * 64 + (((kc * 4 + grp) ^ (col & 7)) << 3)];
        acco[oc] = __builtin_amdgcn_mfma_f32_16x16x32_bf16(ap[kc], bv, acco[oc], 0, 0, 0);
      }
  }
#pragma unroll
  for (int oc = 0; oc < 4; ++oc)
#pragma unroll
    for (int r = 0; r < 4; ++r) {
      int n = n0w + grp * 4 + r;
      int d = oc * 16 + col;
      attn_o[((size_t)(b * SEQ + n)) * CH + h * HD + d] = f2bf(acco[oc][r] / lrun[r]);
    }
}

extern "C" void kernel_launch(void* const* d_in, const int* in_sizes, int n_in,
                              void* d_out, int out_size, void* d_ws, size_t ws_size,
                              hipStream_t stream) {
  const float* x        = (const float*)d_in[0];
  const float* time_emb = (const float*)d_in[1];
  const float* W_qkv    = (const float*)d_in[2];
  const float* b_qkv    = (const float*)d_in[3];
  const float* W_time   = (const float*)d_in[4];
  const float* b_time   = (const float*)d_in[5];
  const float* W_out    = (const float*)d_in[6];
  const float* b_out    = (const float*)d_in[7];
  const float* Er       = (const float*)d_in[8];
  float* out = (float*)d_out;

  char* p = (char*)d_ws;
  float* tqkv = (float*)p;                      p += 98304;
  unsigned short* qb = (unsigned short*)p;      p += 16777216;
  unsigned short* ksw = (unsigned short*)p;     p += 16777216;
  unsigned short* vtsw = (unsigned short*)p;    p += 16777216;
  unsigned short* attn_o = (unsigned short*)p;  p += 16777216;
  unsigned short* Er_bf = (unsigned short*)p;   p += 131072;
  unsigned short* Wout_t = (unsigned short*)p;  p += 2097152;
  unsigned short* x_bf = (unsigned short*)p;               // 16 MB (prep, then dead)
  unsigned short* Wqkv_t = x_bf + (size_t)8388608;         // 6 MB (prep, then dead)
  unsigned short* Gp = (unsigned short*)p;                 // slab Gp, aliases prep region

  size_t fixed = (size_t)(p - (char*)d_ws);
  int slab_bh = (ws_size >= fixed + (size_t)64 * 2099200) ? 64 : 32;
  int nslab = 128 / slab_bh;

  er_convert_kernel<<<256, 256, 0, stream>>>(Er, Er_bf);
  time_proj_kernel<<<96, 256, 0, stream>>>(time_emb, W_time, b_time, tqkv);
  convert_bf_kernel<<<4096, 256, 0, stream>>>(x, x_bf, 1048576);
  transpose_bf_kernel<<<dim3(48, 16), 256, 0, stream>>>(W_qkv, Wqkv_t, 1024, 3072);
  transpose_bf_kernel<<<dim3(16, 16), 256, 0, stream>>>(W_out, Wout_t, 1024, 1024);
  qkv_gemm_mfma<<<dim3(64, 24), 256, 0, stream>>>(x_bf, Wqkv_t, b_qkv, tqkv, qb, ksw, vtsw);
  for (int s = 0; s < nslab; ++s) {
    int bh_base = s * slab_bh;
    g_gemm2<<<dim3(16, 4, slab_bh), 256, 0, stream>>>(qb, bh_base, Er_bf, Gp);
    attn_kernel<<<dim3(16, slab_bh), 256, 0, stream>>>(qb, ksw, vtsw, Gp, attn_o, bh_base);
  }
  out_gemm_mfma<<<dim3(64, 8), 256, 0, stream>>>(attn_o, Wout_t, b_out, out);
}

// Round 8
// 383.714 us; speedup vs baseline: 1.4390x; 1.0371x over previous
//
#include <hip/hip_runtime.h>
#include <math.h>

typedef __attribute__((ext_vector_type(8))) short short8;
typedef __attribute__((ext_vector_type(8))) unsigned short ushort8;
typedef __attribute__((ext_vector_type(4))) unsigned short us4;
typedef __attribute__((ext_vector_type(4))) float f32x4;

#define NH 16
#define HD 64
#define SEQ 1024
#define NB 8
#define CH 1024
#define TD 256
#define GROW 1025  // flat row stride of G' (the skew trick)
#define LOG2E 1.4426950408889634f

__device__ __forceinline__ unsigned short f2bf(float f) {
  union { float f; unsigned int u; } v; v.f = f;
  unsigned int r = v.u + 0x7FFFu + ((v.u >> 16) & 1u);
  return (unsigned short)(r >> 16);
}
__device__ __forceinline__ float bf2f(unsigned short s) {
  union { unsigned int u; float f; } v; v.u = ((unsigned int)s) << 16;
  return v.f;
}
__device__ __forceinline__ float hexp2(float x) {
  float r;
  asm("v_exp_f32 %0, %1" : "=v"(r) : "v"(x));
  return r;
}
__device__ __forceinline__ void gload_lds16(const unsigned short* g, unsigned short* l) {
  __builtin_amdgcn_global_load_lds(
      (const __attribute__((address_space(1))) unsigned int*)g,
      (__attribute__((address_space(3))) unsigned int*)l, 16, 0, 0);
}

// ---------------- time projection (fp32) ----------------
__global__ __launch_bounds__(256) void time_proj_kernel(
    const float* __restrict__ time_emb, const float* __restrict__ W_time,
    const float* __restrict__ b_time, float* __restrict__ tqkv) {
  int idx = blockIdx.x * 256 + threadIdx.x;
  if (idx >= NB * 3072) return;
  int b = idx / 3072, c = idx % 3072;
  float s = b_time[c];
  for (int t = 0; t < TD; ++t) s += time_emb[b * TD + t] * W_time[t * 3072 + c];
  tqkv[idx] = s;
}

// ---------------- Er fp32 -> bf16, scaled by log2e ----------------
__global__ __launch_bounds__(256) void er_convert_kernel(
    const float* __restrict__ Er, unsigned short* __restrict__ Er_bf) {
  int i = blockIdx.x * 256 + threadIdx.x;
  if (i < SEQ * HD) Er_bf[i] = f2bf(Er[i] * LOG2E);
}

// ---------------- fp32 -> bf16 vector convert ----------------
__global__ __launch_bounds__(256) void convert_bf_kernel(
    const float* __restrict__ in, unsigned short* __restrict__ out, int n8) {
  int i = blockIdx.x * 256 + threadIdx.x;
  if (i >= n8) return;
  float4 a = ((const float4*)in)[2 * i];
  float4 b = ((const float4*)in)[2 * i + 1];
  ushort8 o;
  o[0] = f2bf(a.x); o[1] = f2bf(a.y); o[2] = f2bf(a.z); o[3] = f2bf(a.w);
  o[4] = f2bf(b.x); o[5] = f2bf(b.y); o[6] = f2bf(b.z); o[7] = f2bf(b.w);
  ((ushort8*)out)[i] = o;
}

// ---------------- fp32 W[R][C] -> bf16 Wt[C][R] ----------------
__global__ __launch_bounds__(256) void transpose_bf_kernel(
    const float* __restrict__ W, unsigned short* __restrict__ Wt, int R, int Cc) {
  __shared__ float T[64][65];
  int r0 = blockIdx.y * 64, c0 = blockIdx.x * 64;
  for (int idx = threadIdx.x; idx < 4096; idx += 256) {
    int r = idx >> 6, c = idx & 63;
    T[r][c] = W[(size_t)(r0 + r) * Cc + c0 + c];
  }
  __syncthreads();
  for (int idx = threadIdx.x; idx < 4096; idx += 256) {
    int c = idx >> 6, r = idx & 63;
    Wt[(size_t)(c0 + c) * R + r0 + r] = f2bf(T[r][c]);
  }
}

// ---------------- QKV GEMM: bf16 MFMA ----------------
// q -> qb[bh][n][d]
// k -> ksw[bh][n][d ^ ((n&7)<<3)]
// v -> vtsw[bh][d][tile(n) + swz(pi(n&63))], pi(s)=(s&15)*4+(s>>4), swz: granule^=(d&7)
__global__ __launch_bounds__(256) void qkv_gemm_mfma(
    const unsigned short* __restrict__ A, const unsigned short* __restrict__ Bt,
    const float* __restrict__ bqkv, const float* __restrict__ tqkv,
    unsigned short* __restrict__ qb, unsigned short* __restrict__ ksw,
    unsigned short* __restrict__ vtsw) {
  __shared__ unsigned short As[128 * 32];
  __shared__ unsigned short Bs[128 * 32];
  const int m0 = blockIdx.x * 128, n0 = blockIdx.y * 128;
  const int tid = threadIdx.x, l = tid & 63, w = tid >> 6;
  const int wm = w >> 1, wn = w & 1;
  const int grp = l >> 4, col = l & 15;
  f32x4 acc[4][4];
#pragma unroll
  for (int mi = 0; mi < 4; ++mi)
#pragma unroll
    for (int ni = 0; ni < 4; ++ni) acc[mi][ni] = (f32x4){0.f, 0.f, 0.f, 0.f};

  for (int k0 = 0; k0 < 1024; k0 += 32) {
    __syncthreads();
#pragma unroll
    for (int i = 0; i < 2; ++i) {
      int seg = i * 256 + w * 64 + l;
      int mr = seg >> 2, kq = seg & 3;
      gload_lds16(A + (size_t)(m0 + mr) * 1024 + k0 + kq * 8,
                  &As[(i * 256 + w * 64) * 8]);
      gload_lds16(Bt + (size_t)(n0 + mr) * 1024 + k0 + kq * 8,
                  &Bs[(i * 256 + w * 64) * 8]);
    }
    __syncthreads();
    short8 af[4], bfv[4];
#pragma unroll
    for (int mi = 0; mi < 4; ++mi)
      af[mi] = *(const short8*)&As[(wm * 64 + mi * 16 + col) * 32 + grp * 8];
#pragma unroll
    for (int ni = 0; ni < 4; ++ni)
      bfv[ni] = *(const short8*)&Bs[(wn * 64 + ni * 16 + col) * 32 + grp * 8];
#pragma unroll
    for (int mi = 0; mi < 4; ++mi)
#pragma unroll
      for (int ni = 0; ni < 4; ++ni)
        acc[mi][ni] = __builtin_amdgcn_mfma_f32_16x16x32_bf16(af[mi], bfv[ni], acc[mi][ni], 0, 0, 0);
  }

  const int bidx = m0 >> 10;
  const int which = n0 >> 10;
  float biasv[4];
  int hhv[4], dv[4];
#pragma unroll
  for (int ni = 0; ni < 4; ++ni) {
    int c = n0 + wn * 64 + ni * 16 + col;
    biasv[ni] = bqkv[c] + tqkv[bidx * 3072 + c];
    int cc = c & 1023;
    hhv[ni] = cc >> 6;
    dv[ni] = cc & 63;
  }
  if (which == 2) {
    // V: pack across mi (n stride 16) -> contiguous pi-slots; one us4 store each
    int t = (m0 & 1023) + wm * 64;  // 64-aligned tile base of n
#pragma unroll
    for (int ni = 0; ni < 4; ++ni) {
      size_t rowb = ((size_t)(bidx * 16 + hhv[ni]) * 64 + dv[ni]) * 1024;
      int swz = (dv[ni] & 7) << 3;
#pragma unroll
      for (int rr = 0; rr < 4; ++rr) {
        int kbase = (grp * 4 + rr) * 4;  // pi((n&15)) * 4, mi fills +0..3
        int colix = t + ((kbase & ~7) ^ swz) + (kbase & 7);
        us4 pk;
#pragma unroll
        for (int mi = 0; mi < 4; ++mi) pk[mi] = f2bf(acc[mi][ni][rr] + biasv[ni]);
        *(us4*)&vtsw[rowb + colix] = pk;
      }
    }
  } else if (which == 1) {
#pragma unroll
    for (int mi = 0; mi < 4; ++mi)
#pragma unroll
      for (int rr = 0; rr < 4; ++rr) {
        int nn = (m0 + wm * 64 + mi * 16 + grp * 4 + rr) & 1023;
#pragma unroll
        for (int ni = 0; ni < 4; ++ni) {
          size_t bhh = (size_t)(bidx * 16 + hhv[ni]);
          ksw[(bhh * 1024 + nn) * 64 + (dv[ni] ^ ((nn & 7) << 3))] =
              f2bf(acc[mi][ni][rr] + biasv[ni]);
        }
      }
  } else {
#pragma unroll
    for (int mi = 0; mi < 4; ++mi)
#pragma unroll
      for (int rr = 0; rr < 4; ++rr) {
        int nn = (m0 + wm * 64 + mi * 16 + grp * 4 + rr) & 1023;
#pragma unroll
        for (int ni = 0; ni < 4; ++ni) {
          size_t bhh = (size_t)(bidx * 16 + hhv[ni]);
          qb[(bhh * 1024 + nn) * 64 + dv[ni]] = f2bf(acc[mi][ni][rr] + biasv[ni]);
        }
      }
  }
}

// ---------------- output projection: bf16 MFMA ----------------
__global__ __launch_bounds__(256) void out_gemm_mfma(
    const unsigned short* __restrict__ A, const unsigned short* __restrict__ Bt,
    const float* __restrict__ bias, float* __restrict__ out) {
  __shared__ unsigned short As[128 * 32];
  __shared__ unsigned short Bs[128 * 32];
  const int m0 = blockIdx.x * 128, n0 = blockIdx.y * 128;
  const int tid = threadIdx.x, l = tid & 63, w = tid >> 6;
  const int wm = w >> 1, wn = w & 1;
  const int grp = l >> 4, col = l & 15;
  f32x4 acc[4][4];
#pragma unroll
  for (int mi = 0; mi < 4; ++mi)
#pragma unroll
    for (int ni = 0; ni < 4; ++ni) acc[mi][ni] = (f32x4){0.f, 0.f, 0.f, 0.f};

  for (int k0 = 0; k0 < 1024; k0 += 32) {
    __syncthreads();
#pragma unroll
    for (int i = 0; i < 2; ++i) {
      int seg = i * 256 + w * 64 + l;
      int mr = seg >> 2, kq = seg & 3;
      gload_lds16(A + (size_t)(m0 + mr) * 1024 + k0 + kq * 8,
                  &As[(i * 256 + w * 64) * 8]);
      gload_lds16(Bt + (size_t)(n0 + mr) * 1024 + k0 + kq * 8,
                  &Bs[(i * 256 + w * 64) * 8]);
    }
    __syncthreads();
    short8 af[4], bfv[4];
#pragma unroll
    for (int mi = 0; mi < 4; ++mi)
      af[mi] = *(const short8*)&As[(wm * 64 + mi * 16 + col) * 32 + grp * 8];
#pragma unroll
    for (int ni = 0; ni < 4; ++ni)
      bfv[ni] = *(const short8*)&Bs[(wn * 64 + ni * 16 + col) * 32 + grp * 8];
#pragma unroll
    for (int mi = 0; mi < 4; ++mi)
#pragma unroll
      for (int ni = 0; ni < 4; ++ni)
        acc[mi][ni] = __builtin_amdgcn_mfma_f32_16x16x32_bf16(af[mi], bfv[ni], acc[mi][ni], 0, 0, 0);
  }
  float bv[4];
#pragma unroll
  for (int ni = 0; ni < 4; ++ni) bv[ni] = bias[n0 + wn * 64 + ni * 16 + col];
#pragma unroll
  for (int mi = 0; mi < 4; ++mi)
#pragma unroll
    for (int rr = 0; rr < 4; ++rr) {
      int row = m0 + wm * 64 + mi * 16 + grp * 4 + rr;
#pragma unroll
      for (int ni = 0; ni < 4; ++ni) {
        int c = n0 + wn * 64 + ni * 16 + col;
        out[(size_t)row * 1024 + c] = acc[mi][ni][rr] + bv[ni];
      }
    }
}

// ---------------- G' GEMM: G'[n*1025 + j] = q_n . Er'[j]; zero the skew hole ----------------
__global__ __launch_bounds__(256) void g_gemm2(
    const unsigned short* __restrict__ qb, int bh_base,
    const unsigned short* __restrict__ Er_bf,
    unsigned short* __restrict__ Gp) {
  const int n0 = blockIdx.x * 64;
  const int jq = blockIdx.y;       // 0..3
  const int bhl = blockIdx.z;
  const int bh = bh_base + bhl;
  const int tid = threadIdx.x, l = tid & 63, w = tid >> 6;
  const int grp = l >> 4, col = l & 15;
  const int jw = jq * 256 + w * 64;

  short8 aq[4][2];
#pragma unroll
  for (int rf = 0; rf < 4; ++rf)
#pragma unroll
    for (int dc = 0; dc < 2; ++dc)
      aq[rf][dc] = *(const short8*)(qb + ((size_t)bh * SEQ + n0 + rf * 16 + col) * HD + dc * 32 + grp * 8);

  f32x4 acc[4][4];
#pragma unroll
  for (int rf = 0; rf < 4; ++rf)
#pragma unroll
    for (int cf = 0; cf < 4; ++cf) acc[rf][cf] = (f32x4){0.f, 0.f, 0.f, 0.f};

#pragma unroll
  for (int cf = 0; cf < 4; ++cf)
#pragma unroll
    for (int dc = 0; dc < 2; ++dc) {
      short8 bfrag = *(const short8*)(Er_bf + (size_t)(jw + cf * 16 + col) * HD + dc * 32 + grp * 8);
#pragma unroll
      for (int rf = 0; rf < 4; ++rf)
        acc[rf][cf] = __builtin_amdgcn_mfma_f32_16x16x32_bf16(aq[rf][dc], bfrag, acc[rf][cf], 0, 0, 0);
    }

#pragma unroll
  for (int rf = 0; rf < 4; ++rf)
#pragma unroll
    for (int cf = 0; cf < 4; ++cf)
#pragma unroll
      for (int rr = 0; rr < 4; ++rr) {
        int n = n0 + rf * 16 + grp * 4 + rr;
        int j = jw + cf * 16 + col;
        Gp[((size_t)(bhl * SEQ + n)) * GROW + j] = f2bf(acc[rf][cf][rr]);
      }
  // zero the skew's dropped-pad hole (flat n*1025+1024) so attn needs no mask
  if (jq == 3 && tid < 64) {
    int n = n0 + tid;
    Gp[((size_t)(bhl * SEQ + n)) * GROW + 1024] = 0;
  }
}

// ---------------- flash attention: 2-phase pipelined ----------------
__global__ __launch_bounds__(256) void attn_kernel(
    const unsigned short* __restrict__ qb, const unsigned short* __restrict__ ksw,
    const unsigned short* __restrict__ vtsw, const unsigned short* __restrict__ Gp,
    unsigned short* __restrict__ attn_o, int bh_base) {
  __shared__ __align__(16) unsigned short KsL[2][4096];
  __shared__ __align__(16) unsigned short VtL[2][4096];
  __shared__ __align__(16) unsigned short Band[2][64][72];
  __shared__ __align__(16) unsigned short Pw[4][16][72];

  // XCD-chunked remap: contiguous bh ranges per XCD
  const int wg = blockIdx.x + 16 * blockIdx.y;
  const int chunk = 2 * gridDim.y;  // nwg/8
  const int nid = (wg & 7) * chunk + (wg >> 3);
  const int bhl = nid >> 4;
  const int n0 = (nid & 15) * 64;
  const int bh = bh_base + bhl;
  const int b = bh >> 4, h = bh & 15;
  const int tid = threadIdx.x, lane = tid & 63, wq = tid >> 6;
  const int grp = lane >> 4, col = lane & 15;
  const int n0w = n0 + wq * 16;

  short8 aq[2];
#pragma unroll
  for (int dc = 0; dc < 2; ++dc)
    aq[dc] = *(const short8*)(qb + ((size_t)(bh * SEQ + n0w + col)) * HD + dc * 32 + grp * 8);

  f32x4 acco[4];
#pragma unroll
  for (int oc = 0; oc < 4; ++oc) acco[oc] = (f32x4){0.f, 0.f, 0.f, 0.f};
  float mrun[4], lrun[4];  // lrun is a PER-LANE partial (reduced in epilogue)
#pragma unroll
  for (int r = 0; r < 4; ++r) { mrun[r] = -INFINITY; lrun[r] = 0.f; }

  const float scale2 = 0.125f * LOG2E;  // log2-domain scale (Er carries log2e)
  const unsigned short* kbh = ksw + (size_t)bh * SEQ * HD;   // [m][d^((m&7)<<3)]
  const unsigned short* vbh = vtsw + (size_t)bh * HD * SEQ;  // [d][tile+swz(pi)]
  const unsigned short* gbase = Gp + (size_t)(bhl * SEQ + n0) * GROW + (1016 - n0);

  auto STAGE = [&](int buf, int m0) {
#pragma unroll
    for (int i = 0; i < 2; ++i) {
      int gi = i * 256 + wq * 64 + lane;
      int row = gi >> 3, gc = gi & 7;
      gload_lds16(kbh + (((size_t)(m0 + row)) << 6) + gc * 8,
                  &KsL[buf][(i * 256 + wq * 64) * 8]);
      gload_lds16(vbh + (((size_t)row) << 10) + m0 + gc * 8,
                  &VtL[buf][(i * 256 + wq * 64) * 8]);
    }
    const unsigned short* gsrc = gbase + m0;
    unsigned short* bdst = &Band[buf][0][0];
    const int g0 = wq * 144;
#pragma unroll
    for (int it = 0; it < 2; ++it) {
      int g = g0 + it * 64 + lane;
      int r = g / 9, seg = g - r * 9;
      gload_lds16(gsrc + r * 1024 + seg * 8, bdst + g * 8);
    }
    if (lane < 16) {
      int g = g0 + 128 + lane;
      int r = g / 9, seg = g - r * 9;
      gload_lds16(gsrc + r * 1024 + seg * 8, bdst + g * 8);
    }
  };

  STAGE(0, 0);
  __syncthreads();

  for (int t = 0; t < 16; ++t) {
    const int cur = t & 1;
    if (t < 15) STAGE(cur ^ 1, (t + 1) * 64);  // prefetch hides under compute
    // QK^T
    f32x4 acc[4];
#pragma unroll
    for (int mc = 0; mc < 4; ++mc) acc[mc] = (f32x4){0.f, 0.f, 0.f, 0.f};
#pragma unroll
    for (int mc = 0; mc < 4; ++mc)
#pragma unroll
      for (int dc = 0; dc < 2; ++dc) {
        short8 bk = *(const short8*)&KsL[cur][(mc * 16 + col) * 64 + (((dc * 4 + grp) ^ (col & 7)) << 3)];
        acc[mc] = __builtin_amdgcn_mfma_f32_16x16x32_bf16(aq[dc], bk, acc[mc], 0, 0, 0);
      }
    // online softmax in log2 domain (per-lane partial lrun, group-uniform rescale)
#pragma unroll
    for (int r = 0; r < 4; ++r) {
      int dr = wq * 16 + grp * 4 + r;
      float s[4];
#pragma unroll
      for (int mc = 0; mc < 4; ++mc)
        s[mc] = fmaf(acc[mc][r], scale2, bf2f(Band[cur][dr][7 + mc * 16 + col]));
      float mx = fmaxf(fmaxf(s[0], s[1]), fmaxf(s[2], s[3]));
#pragma unroll
      for (int off = 1; off < 16; off <<= 1) mx = fmaxf(mx, __shfl_xor(mx, off));
      if (mx > mrun[r]) {
        float cr = hexp2(mrun[r] - mx);
        mrun[r] = mx;
        lrun[r] *= cr;
#pragma unroll
        for (int oc = 0; oc < 4; ++oc) acco[oc][r] *= cr;
      }
      float p0 = hexp2(s[0] - mrun[r]);
      float p1 = hexp2(s[1] - mrun[r]);
      float p2 = hexp2(s[2] - mrun[r]);
      float p3 = hexp2(s[3] - mrun[r]);
      lrun[r] += (p0 + p1) + (p2 + p3);
      unsigned int r01, r23;
      asm("v_cvt_pk_bf16_f32 %0, %1, %2" : "=v"(r01) : "v"(p0), "v"(p1));
      asm("v_cvt_pk_bf16_f32 %0, %1, %2" : "=v"(r23) : "v"(p2), "v"(p3));
      unsigned long long pk = (unsigned long long)r01 | ((unsigned long long)r23 << 32);
      *(unsigned long long*)&Pw[wq][grp * 4 + r][col * 4] = pk;  // pi-slots col*4+mc
    }
    // PV (k-dim in pi-order on BOTH operands)
    short8 ap[2];
#pragma unroll
    for (int kc = 0; kc < 2; ++kc)
      ap[kc] = *(const short8*)&Pw[wq][col][kc * 32 + grp * 8];
#pragma unroll
    for (int oc = 0; oc < 4; ++oc)
#pragma unroll
      for (int kc = 0; kc < 2; ++kc) {
        short8 bv = *(const short8*)&VtL[cur][(oc * 16 + col) * 64 + (((kc * 4 + grp) ^ (col & 7)) << 3)];
        acco[oc] = __builtin_amdgcn_mfma_f32_16x16x32_bf16(ap[kc], bv, acco[oc], 0, 0, 0);
      }
    __syncthreads();  // drains prefetch vmcnt + protects buf reuse
  }
  // epilogue: reduce per-lane lrun partials across the 16-lane group, then store
#pragma unroll
  for (int r = 0; r < 4; ++r) {
    float tot = lrun[r];
#pragma unroll
    for (int off = 1; off < 16; off <<= 1) tot += __shfl_xor(tot, off);
    float inv = 1.0f / tot;
    int n = n0w + grp * 4 + r;
#pragma unroll
    for (int oc = 0; oc < 4; ++oc) {
      int d = oc * 16 + col;
      attn_o[((size_t)(b * SEQ + n)) * CH + h * HD + d] = f2bf(acco[oc][r] * inv);
    }
  }
}

extern "C" void kernel_launch(void* const* d_in, const int* in_sizes, int n_in,
                              void* d_out, int out_size, void* d_ws, size_t ws_size,
                              hipStream_t stream) {
  const float* x        = (const float*)d_in[0];
  const float* time_emb = (const float*)d_in[1];
  const float* W_qkv    = (const float*)d_in[2];
  const float* b_qkv    = (const float*)d_in[3];
  const float* W_time   = (const float*)d_in[4];
  const float* b_time   = (const float*)d_in[5];
  const float* W_out    = (const float*)d_in[6];
  const float* b_out    = (const float*)d_in[7];
  const float* Er       = (const float*)d_in[8];
  float* out = (float*)d_out;

  char* p = (char*)d_ws;
  float* tqkv = (float*)p;                      p += 98304;
  unsigned short* qb = (unsigned short*)p;      p += 16777216;
  unsigned short* ksw = (unsigned short*)p;     p += 16777216;
  unsigned short* vtsw = (unsigned short*)p;    p += 16777216;
  unsigned short* attn_o = (unsigned short*)p;  p += 16777216;
  unsigned short* Er_bf = (unsigned short*)p;   p += 131072;
  unsigned short* Wout_t = (unsigned short*)p;  p += 2097152;
  unsigned short* x_bf = (unsigned short*)p;               // 16 MB (prep, then dead)
  unsigned short* Wqkv_t = x_bf + (size_t)8388608;         // 6 MB (prep, then dead)
  unsigned short* Gp = (unsigned short*)p;                 // slab Gp, aliases prep region

  size_t fixed = (size_t)(p - (char*)d_ws);
  int slab_bh = (ws_size >= fixed + (size_t)64 * 2099200) ? 64 : 32;
  int nslab = 128 / slab_bh;

  er_convert_kernel<<<256, 256, 0, stream>>>(Er, Er_bf);
  time_proj_kernel<<<96, 256, 0, stream>>>(time_emb, W_time, b_time, tqkv);
  convert_bf_kernel<<<4096, 256, 0, stream>>>(x, x_bf, 1048576);
  transpose_bf_kernel<<<dim3(48, 16), 256, 0, stream>>>(W_qkv, Wqkv_t, 1024, 3072);
  transpose_bf_kernel<<<dim3(16, 16), 256, 0, stream>>>(W_out, Wout_t, 1024, 1024);
  qkv_gemm_mfma<<<dim3(64, 24), 256, 0, stream>>>(x_bf, Wqkv_t, b_qkv, tqkv, qb, ksw, vtsw);
  for (int s = 0; s < nslab; ++s) {
    int bh_base = s * slab_bh;
    g_gemm2<<<dim3(16, 4, slab_bh), 256, 0, stream>>>(qb, bh_base, Er_bf, Gp);
    attn_kernel<<<dim3(16, slab_bh), 256, 0, stream>>>(qb, ksw, vtsw, Gp, attn_o, bh_base);
  }
  out_gemm_mfma<<<dim3(64, 8), 256, 0, stream>>>(attn_o, Wout_t, b_out, out);
}